// Round 2
// baseline (910.678 us; speedup 1.0000x reference)
//
#include <hip/hip_runtime.h>
#include <stdint.h>

typedef unsigned int u32;
typedef unsigned long long u64;

#define BIMG 8
#define NPROP 4000
#define NCLS 91
#define CM1 90
#define MCAND (NPROP * CM1)      // 360000 candidates per image
#define KPRE 2048
#define NBUCKET 4096
#define SELCAP 16384
#define DETS 100
#define SCORE_T 0.05f
#define NMS_T 0.5f
#define BBOX_CLIP 4.135166556742356f   // log(1000/16)

// ---------------- workspace layout ----------------
#define HIST_OFF   ((size_t)0)                               // u32[8][4096]
#define BCNT_OFF   (HIST_OFF + (size_t)BIMG * NBUCKET * 4)   // u32[8][4096]
#define META_OFF   (BCNT_OFF + (size_t)BIMG * NBUCKET * 4)   // u32[8][8]: V, T, fillneed
#define ZERO_BYTES (META_OFF + 4096)
#define START_OFF  (ZERO_BYTES)                              // u32[8][4096]
#define SEL_OFF    (START_OFF + (size_t)BIMG * NBUCKET * 4)  // u64[8][SELCAP]
#define TBOX_OFF   (SEL_OFF + (size_t)BIMG * SELCAP * 8)     // f32[8][2048][4]
#define TSB_OFF    (TBOX_OFF + (size_t)BIMG * KPRE * 16)     // f32[8][2048][4] shifted
#define TSC_OFF    (TSB_OFF + (size_t)BIMG * KPRE * 16)      // f32[8][2048]
#define TLB_OFF    (TSC_OFF + (size_t)BIMG * KPRE * 4)       // i32[8][2048]
#define TVL_OFF    (TLB_OFF + (size_t)BIMG * KPRE * 4)       // u32[8][2048]
#define KEEP_OFF   (TVL_OFF + (size_t)BIMG * KPRE * 4)       // u64[8][32]
#define MASK_OFF   (KEEP_OFF + (size_t)BIMG * 32 * 8)        // u64[8][2048][32]
#define CAND_OFF   (MASK_OFF + (size_t)BIMG * KPRE * 32 * 8) // u32[8][360000]
#define WS_NEED    (CAND_OFF + (size_t)BIMG * MCAND * 4)

__device__ __forceinline__ void decode_clip(const float4 rg, const float w, const float h,
                                            const float cx, const float cy,
                                            const float fw, const float fh, float bx[4]) {
    float dx = rg.x / 10.0f;
    float dy = rg.y / 10.0f;
    float dw = fminf(rg.z / 5.0f, BBOX_CLIP);
    float dh = fminf(rg.w / 5.0f, BBOX_CLIP);
    float pcx = dx * w + cx;
    float pcy = dy * h + cy;
    float pw  = expf(dw) * w;
    float phh = expf(dh) * h;
    bx[0] = fminf(fmaxf(pcx - 0.5f * pw,  0.0f), fw);
    bx[1] = fminf(fmaxf(pcy - 0.5f * phh, 0.0f), fh);
    bx[2] = fminf(fmaxf(pcx + 0.5f * pw,  0.0f), fw);
    bx[3] = fminf(fmaxf(pcy + 0.5f * phh, 0.0f), fh);
}

// K1: one wave per proposal row. Softmax(91), decode+clip 90 class boxes,
// validity mask; store order-preserving score bits (0 = invalid) and histogram
// valid candidates into 4096 buckets (top 12 bits of ord).
__global__ __launch_bounds__(256) void k1_score_hist(
    const float* __restrict__ logits, const float* __restrict__ reg,
    const float* __restrict__ props, const int* __restrict__ imh, const int* __restrict__ imw,
    u32* __restrict__ hist, u32* __restrict__ cand_ord) {
    const int lane = threadIdx.x & 63;
    const int pid = blockIdx.x * 4 + (threadIdx.x >> 6);
    if (pid >= BIMG * NPROP) return;
    const int img = pid / NPROP;
    const float fw = (float)imw[0], fh = (float)imh[0];
    const float* lrow = logits + (size_t)pid * NCLS;
    float v0 = lrow[lane];
    float v1 = (lane < 27) ? lrow[lane + 64] : -3.0e38f;
    float mx = fmaxf(v0, v1);
#pragma unroll
    for (int o = 32; o > 0; o >>= 1) mx = fmaxf(mx, __shfl_xor(mx, o));
    float es = expf(v0 - mx) + ((lane < 27) ? expf(v1 - mx) : 0.0f);
#pragma unroll
    for (int o = 32; o > 0; o >>= 1) es += __shfl_xor(es, o);
    float4 p = reinterpret_cast<const float4*>(props)[pid];
    const float w = p.z - p.x, h = p.w - p.y;
    const float cx = p.x + 0.5f * w, cy = p.y + 0.5f * h;
    const float4* rrow = reinterpret_cast<const float4*>(reg) + (size_t)pid * NCLS;
    u32* co = cand_ord + (size_t)img * MCAND + (size_t)(pid - img * NPROP) * CM1;
#pragma unroll
    for (int batch = 0; batch < 2; ++batch) {
        int ci = lane + batch * 64;
        if (ci < CM1) {
            int c = ci + 1;
            float sc = expf(lrow[c] - mx) / es;
            float4 rg = rrow[c];
            float bx[4];
            decode_clip(rg, w, h, cx, cy, fw, fh, bx);
            bool valid = (sc > SCORE_T) && (bx[2] - bx[0] >= 1.0f) && (bx[3] - bx[1] >= 1.0f);
            u32 o = 0u;
            if (valid) {
                o = __float_as_uint(sc) | 0x80000000u;  // sc > 0 always
                atomicAdd(&hist[img * NBUCKET + (o >> 20)], 1u);
            }
            co[ci] = o;
        }
    }
}

// K2: one wave per image. Reverse (descending-bucket) exclusive scan of the
// histogram -> start[], threshold bucket T straddling rank KPRE, V, fillneed.
__global__ __launch_bounds__(64) void k2_scan(
    const u32* __restrict__ hist, u32* __restrict__ start, u32* __restrict__ meta) {
    const int img = blockIdx.x;
    const int lane = threadIdx.x;
    u32 base = 0;
    int T = -1;
    for (int chunk = 63; chunk >= 0; --chunk) {
        int bucket = chunk * 64 + 63 - lane;   // lane order = descending bucket
        u32 cnt = hist[img * NBUCKET + bucket];
        u32 inc = cnt;
#pragma unroll
        for (int o = 1; o < 64; o <<= 1) {
            u32 t = __shfl_up(inc, o);
            if (lane >= o) inc += t;
        }
        u32 excl = base + inc - cnt;
        start[img * NBUCKET + bucket] = excl;
        bool cross = (cnt > 0) && (excl < KPRE) && (excl + cnt >= KPRE);
        u64 bal = __ballot(cross);
        if (T < 0 && bal != 0ull) {
            int l = __ffsll(bal) - 1;
            T = chunk * 64 + 63 - l;
        }
        base += __shfl(inc, 63);
    }
    if (lane == 0) {
        meta[img * 8 + 0] = base;                                  // V = total valid
        meta[img * 8 + 1] = (T >= 0) ? (u32)T : 0u;                // threshold bucket
        meta[img * 8 + 2] = (base < KPRE) ? (KPRE - base) : 0u;    // fill needed
    }
}

// K3: compact candidates in buckets >= T into sel[], placed at bucket-start +
// within-bucket atomic position. Key = ord<<32 | ~idx (desc value, asc index).
__global__ __launch_bounds__(256) void k3_compact(
    const u32* __restrict__ cand_ord, const u32* __restrict__ start,
    const u32* __restrict__ meta, u32* __restrict__ bcnt, u64* __restrict__ sel) {
    const u32 t = blockIdx.x * 256 + threadIdx.x;
    if (t >= (u32)(BIMG * MCAND)) return;
    const int img = t / MCAND;
    const u32 idx = t - (u32)img * MCAND;
    const u32 o = cand_ord[t];
    if (!o) return;
    const u32 bk = o >> 20;
    if (bk < meta[img * 8 + 1]) return;
    const u32 pos = start[img * NBUCKET + bk] + atomicAdd(&bcnt[img * NBUCKET + bk], 1u);
    if (pos < SELCAP)
        sel[(size_t)img * SELCAP + pos] = ((u64)o << 32) | (u32)(~idx);
}

// K3b: rare path — fewer than KPRE valid: fill remaining slots with invalid
// candidates (score -1) in ascending-index order (lax.top_k tie semantics).
__global__ __launch_bounds__(64) void k3b_fill(
    const u32* __restrict__ cand_ord, const u32* __restrict__ meta, u64* __restrict__ sel) {
    const int img = blockIdx.x;
    const u32 need = meta[img * 8 + 2];
    if (need == 0) return;
    const u32 V = meta[img * 8 + 0];
    const int lane = threadIdx.x;
    const u32 ORDN1 = 0x407FFFFFu;  // ord_of(-1.0f)
    u32 filled = 0;
    for (u32 b0 = 0; b0 < MCAND && filled < need; b0 += 64) {
        u32 idx = b0 + lane;
        bool inv = (idx < MCAND) && (cand_ord[(size_t)img * MCAND + idx] == 0u);
        u64 bal = __ballot(inv);
        u32 pre = (u32)__popcll(bal & ((1ull << lane) - 1ull));
        if (inv && (filled + pre) < need)
            sel[(size_t)img * SELCAP + V + filled + pre] = ((u64)ORDN1 << 32) | (u32)(~idx);
        filled += (u32)__popcll(bal);
    }
}

// K4: sort each compacted bucket segment (those intersecting the top-KPRE
// region) descending by key via LDS bitonic. Segments are disjoint and already
// in global descending-bucket order, so afterwards sel[0..2047] is the exact
// top-2048 in lax.top_k order.
__global__ __launch_bounds__(256) void k4_sortseg(
    const u32* __restrict__ hist, const u32* __restrict__ start, u64* __restrict__ sel) {
    __shared__ u64 arr[4096];
    const int img = blockIdx.y;
    const int tid = threadIdx.x;
    for (int bk = blockIdx.x * 16; bk < blockIdx.x * 16 + 16; ++bk) {
        u32 cnt = hist[img * NBUCKET + bk];          // uniform across block
        if (cnt < 2) continue;
        u32 st = start[img * NBUCKET + bk];
        if (st >= KPRE) continue;                    // below top region
        if (st + cnt > SELCAP) cnt = SELCAP - st;
        if (cnt > 4096) cnt = 4096;                  // pathological only
        int n = 1;
        while (n < (int)cnt) n <<= 1;
        u64* seg = sel + (size_t)img * SELCAP + st;
        for (int i = tid; i < n; i += 256) arr[i] = (i < (int)cnt) ? seg[i] : 0ull;
        __syncthreads();
        for (int k = 2; k <= n; k <<= 1)
            for (int j = k >> 1; j > 0; j >>= 1) {
                for (int i = tid; i < n; i += 256) {
                    int ixj = i ^ j;
                    if (ixj > i) {
                        u64 a = arr[i], b = arr[ixj];
                        bool swp = ((i & k) == 0) ? (a < b) : (a > b);
                        if (swp) { arr[i] = b; arr[ixj] = a; }
                    }
                }
                __syncthreads();
            }
        for (int i = tid; i < (int)cnt; i += 256) seg[i] = arr[i];
        __syncthreads();
    }
}

// K5: gather the top-2048: re-decode boxes, store score/label/valid, compute
// max coordinate and class-offset shifted boxes exactly as the reference.
__global__ __launch_bounds__(256) void k5_gather(
    const u64* __restrict__ sel, const float* __restrict__ reg, const float* __restrict__ props,
    const int* __restrict__ imh, const int* __restrict__ imw,
    float* __restrict__ tbox, float* __restrict__ tsb, float* __restrict__ tsc,
    int* __restrict__ tlb, u32* __restrict__ tvl) {
    const int img = blockIdx.x;
    const int tid = threadIdx.x;
    const float fw = (float)imw[0], fh = (float)imh[0];
    float bx[8][4];
    int lab[8];
    float lm = -3.0e38f;
#pragma unroll
    for (int t = 0; t < 8; ++t) {
        int s = t * 256 + tid;
        u64 key = sel[(size_t)img * SELCAP + s];
        u32 o = (u32)(key >> 32);
        u32 idx = ~((u32)key);
        u32 b = (o & 0x80000000u) ? (o & 0x7FFFFFFFu) : ~o;
        float sc = __uint_as_float(b);               // exact masked score roundtrip
        u32 n = idx / CM1;
        int c = (int)(idx - n * CM1) + 1;
        int pid = img * NPROP + (int)n;
        float4 p = reinterpret_cast<const float4*>(props)[pid];
        float w = p.z - p.x, h = p.w - p.y;
        float cx = p.x + 0.5f * w, cy = p.y + 0.5f * h;
        float4 rg = reinterpret_cast<const float4*>(reg)[(size_t)pid * NCLS + c];
        decode_clip(rg, w, h, cx, cy, fw, fh, bx[t]);
        lab[t] = c;
        lm = fmaxf(lm, fmaxf(fmaxf(bx[t][0], bx[t][1]), fmaxf(bx[t][2], bx[t][3])));
        reinterpret_cast<float4*>(tbox)[(size_t)img * KPRE + s] =
            make_float4(bx[t][0], bx[t][1], bx[t][2], bx[t][3]);
        tsc[(size_t)img * KPRE + s] = sc;
        tlb[(size_t)img * KPRE + s] = c;
        tvl[(size_t)img * KPRE + s] = (sc > SCORE_T) ? 1u : 0u;
    }
#pragma unroll
    for (int o2 = 32; o2 > 0; o2 >>= 1) lm = fmaxf(lm, __shfl_xor(lm, o2));
    __shared__ float wm[4];
    if ((tid & 63) == 0) wm[tid >> 6] = lm;
    __syncthreads();
    float mplus = fmaxf(fmaxf(wm[0], wm[1]), fmaxf(wm[2], wm[3])) + 1.0f;
#pragma unroll
    for (int t = 0; t < 8; ++t) {
        int s = t * 256 + tid;
        float off = (float)lab[t] * mplus;
        reinterpret_cast<float4*>(tsb)[(size_t)img * KPRE + s] =
            make_float4(bx[t][0] + off, bx[t][1] + off, bx[t][2] + off, bx[t][3] + off);
    }
}

// K6: suppression bitmask. Block = 64 rows x 64 cols; bit set iff
// iou(shifted_i, shifted_j) > thresh and j > i (reference formula verbatim).
__global__ __launch_bounds__(64) void k6_mask(
    const float* __restrict__ tsb, u64* __restrict__ mask) {
    const int img = blockIdx.z;
    const int j0 = blockIdx.x * 64;
    const int i0 = blockIdx.y * 64;
    const int tid = threadIdx.x;
    __shared__ float4 cb[64];
    __shared__ float ca[64];
    float4 c = reinterpret_cast<const float4*>(tsb)[(size_t)img * KPRE + j0 + tid];
    cb[tid] = c;
    ca[tid] = (c.z - c.x) * (c.w - c.y);
    __syncthreads();
    const int i = i0 + tid;
    float4 r = reinterpret_cast<const float4*>(tsb)[(size_t)img * KPRE + i];
    float ra = (r.z - r.x) * (r.w - r.y);
    u64 bits = 0ull;
#pragma unroll 8
    for (int jj = 0; jj < 64; ++jj) {
        int j = j0 + jj;
        float4 cc = cb[jj];
        float wv = fmaxf(fminf(r.z, cc.z) - fmaxf(r.x, cc.x), 0.0f);
        float hv = fmaxf(fminf(r.w, cc.w) - fmaxf(r.y, cc.y), 0.0f);
        float inter = wv * hv;
        float iou = inter / ((ra + ca[jj]) - inter);   // NaN compares false, like jnp
        if ((iou > NMS_T) && (j > i)) bits |= (1ull << jj);
    }
    mask[((size_t)img * KPRE + i) * 32 + (j0 >> 6)] = bits;
}

// K7: greedy scan, one wave per image. The serial chain is kept entirely in
// VALU registers: rem_cur = removed word for the CURRENT 64-row block,
// replicated uniformly in all lanes; bit test uses a compile-time-constant
// mask (full 64-unroll). Row data arrives via two prefetched load streams
// (distributed full row for lanes 0..31, uniform broadcast of the same-block
// word) that never sit on the serial dependency chain. One u64 shfl per
// 64-row block transition (32 total) is the only cross-lane op on the chain.
__global__ __launch_bounds__(64) void k7_nms(
    const u64* __restrict__ mask, const u32* __restrict__ tvl, u64* __restrict__ keepw) {
    const int img = blockIdx.x;
    const int lane = threadIdx.x;
    // distributed removed: lane l (<32) holds word l; invalid rows pre-removed
    u64 removed = ~0ull;
    for (int w = 0; w < 32; ++w) {
        bool tv = tvl[(size_t)img * KPRE + w * 64 + lane] != 0u;
        u64 bal = __ballot(tv);
        if (lane == w) removed = ~bal;
    }
    const u64* mrow = mask + (size_t)img * KPRE * 32;
    constexpr int PD = 32;
    u64 dbuf[PD];   // distributed row i: lane l<32 holds word l
    u64 wbuf[PD];   // uniform: word (i>>6) of row i (same value in all lanes)
#pragma unroll
    for (int t = 0; t < PD; ++t) {
        dbuf[t] = (lane < 32) ? mrow[(size_t)t * 32 + lane] : 0ull;
        wbuf[t] = mrow[(size_t)t * 32 + 0];          // rows 0..31 are in block 0
    }
    u64 rem_cur = __shfl(removed, 0);                // block 0's removed word, all lanes
    for (int base = 0; base < KPRE; base += 64) {
#pragma unroll
        for (int u = 0; u < 64; ++u) {
            const int i = base + u;
            const int slot = u & (PD - 1);
            const u64 dv = dbuf[slot];
            const u64 wv = wbuf[slot];
            const int nx = i + PD;
            if (nx < KPRE) {                          // uniform branch
                dbuf[slot] = (lane < 32) ? mrow[(size_t)nx * 32 + lane] : 0ull;
                wbuf[slot] = mrow[(size_t)nx * 32 + (nx >> 6)];
            }
            const bool kept = (rem_cur & (1ull << u)) == 0ull;  // constant mask
            rem_cur |= kept ? wv : 0ull;             // serial chain: ~3 VALU ops
            removed |= kept ? dv : 0ull;             // off-chain distributed update
        }
        const int wnext = (base >> 6) + 1;
        if (wnext < 32) rem_cur = __shfl(removed, wnext);  // once per 64 rows
    }
    if (lane < 32) keepw[img * 32 + lane] = ~removed;
}

// K8: final top-100 per image (bitonic over 2048 keys) + output writes.
__global__ __launch_bounds__(256) void k8_final(
    const u64* __restrict__ keepw, const float* __restrict__ tsc,
    const float* __restrict__ tbox, const int* __restrict__ tlb,
    float* __restrict__ out) {
    __shared__ u64 arr[KPRE];
    const int img = blockIdx.x;
    const int tid = threadIdx.x;
#pragma unroll
    for (int t = 0; t < 8; ++t) {
        int s = t * 256 + tid;
        u64 kw = keepw[img * 32 + (s >> 6)];
        bool kept = (kw >> (s & 63)) & 1ull;
        float ks = kept ? tsc[(size_t)img * KPRE + s] : -1.0f;
        u32 b = __float_as_uint(ks);
        u32 o = (b & 0x80000000u) ? ~b : (b | 0x80000000u);
        arr[s] = ((u64)o << 32) | (u32)(~(u32)s);
    }
    __syncthreads();
    for (int k = 2; k <= KPRE; k <<= 1)
        for (int j = k >> 1; j > 0; j >>= 1) {
            for (int i = tid; i < KPRE; i += 256) {
                int ixj = i ^ j;
                if (ixj > i) {
                    u64 a = arr[i], bb = arr[ixj];
                    bool swp = ((i & k) == 0) ? (a < bb) : (a > bb);
                    if (swp) { arr[i] = bb; arr[ixj] = a; }
                }
            }
            __syncthreads();
        }
    if (tid < DETS) {
        u64 key = arr[tid];
        u32 o = (u32)(key >> 32);
        u32 b = (o & 0x80000000u) ? (o & 0x7FFFFFFFu) : ~o;
        float fs = __uint_as_float(b);
        u32 s = ~((u32)key);
        bool fv = fs > SCORE_T;
        float4 bxv = make_float4(0.0f, 0.0f, 0.0f, 0.0f);
        float lb = -1.0f, scw = 0.0f;
        if (fv) {
            bxv = reinterpret_cast<const float4*>(tbox)[(size_t)img * KPRE + s];
            lb = (float)tlb[(size_t)img * KPRE + s];
            scw = fs;
        }
        float* ob = out + (size_t)img * DETS * 4 + (size_t)tid * 4;
        ob[0] = bxv.x; ob[1] = bxv.y; ob[2] = bxv.z; ob[3] = bxv.w;
        out[BIMG * DETS * 4 + img * DETS + tid] = scw;   // scores at 3200
        out[BIMG * DETS * 5 + img * DETS + tid] = lb;    // labels at 4000
    }
}

extern "C" void kernel_launch(void* const* d_in, const int* in_sizes, int n_in,
                              void* d_out, int out_size, void* d_ws, size_t ws_size,
                              hipStream_t stream) {
    const float* logits = (const float*)d_in[0];
    const float* reg    = (const float*)d_in[1];
    const float* props  = (const float*)d_in[2];
    const int*   imh    = (const int*)d_in[3];
    const int*   imw    = (const int*)d_in[4];
    float* out = (float*)d_out;
    char* ws = (char*)d_ws;
    if (ws_size < WS_NEED) return;  // ~17.1 MB needed

    u32* hist = (u32*)(ws + HIST_OFF);
    u32* bcnt = (u32*)(ws + BCNT_OFF);
    u32* meta = (u32*)(ws + META_OFF);
    u32* start = (u32*)(ws + START_OFF);
    u64* sel  = (u64*)(ws + SEL_OFF);
    float* tbox = (float*)(ws + TBOX_OFF);
    float* tsb  = (float*)(ws + TSB_OFF);
    float* tsc  = (float*)(ws + TSC_OFF);
    int*   tlb  = (int*)(ws + TLB_OFF);
    u32*   tvl  = (u32*)(ws + TVL_OFF);
    u64*   keepw = (u64*)(ws + KEEP_OFF);
    u64*   mask = (u64*)(ws + MASK_OFF);
    u32*   cand_ord = (u32*)(ws + CAND_OFF);

    hipMemsetAsync(d_ws, 0, ZERO_BYTES, stream);  // hist, bcnt, meta

    k1_score_hist<<<BIMG * NPROP / 4, 256, 0, stream>>>(logits, reg, props, imh, imw,
                                                        hist, cand_ord);
    k2_scan<<<BIMG, 64, 0, stream>>>(hist, start, meta);
    k3_compact<<<(BIMG * MCAND) / 256, 256, 0, stream>>>(cand_ord, start, meta, bcnt, sel);
    k3b_fill<<<BIMG, 64, 0, stream>>>(cand_ord, meta, sel);
    k4_sortseg<<<dim3(256, BIMG), 256, 0, stream>>>(hist, start, sel);
    k5_gather<<<BIMG, 256, 0, stream>>>(sel, reg, props, imh, imw, tbox, tsb, tsc, tlb, tvl);
    k6_mask<<<dim3(32, 32, BIMG), 64, 0, stream>>>(tsb, mask);
    k7_nms<<<BIMG, 64, 0, stream>>>(mask, tvl, keepw);
    k8_final<<<BIMG, 256, 0, stream>>>(keepw, tsc, tbox, tlb, out);
}

// Round 3
// 585.583 us; speedup vs baseline: 1.5552x; 1.5552x over previous
//
#include <hip/hip_runtime.h>
#include <stdint.h>

typedef unsigned int u32;
typedef unsigned long long u64;

#define BIMG 8
#define NPROP 4000
#define NCLS 91
#define CM1 90
#define MCAND (NPROP * CM1)      // 360000 candidates per image
#define KPRE 2048
#define NBUCKET 4096
#define SELCAP 16384
#define DETS 100
#define SCORE_T 0.05f
#define NMS_T 0.5f
#define BBOX_CLIP 4.135166556742356f   // log(1000/16)

// ---------------- workspace layout ----------------
#define HIST_OFF   ((size_t)0)                               // u32[8][4096]
#define BCNT_OFF   (HIST_OFF + (size_t)BIMG * NBUCKET * 4)   // u32[8][4096]
#define META_OFF   (BCNT_OFF + (size_t)BIMG * NBUCKET * 4)   // u32[8][8]: V, T, fillneed
#define ZERO_BYTES (META_OFF + 4096)
#define START_OFF  (ZERO_BYTES)                              // u32[8][4096]
#define SEL_OFF    (START_OFF + (size_t)BIMG * NBUCKET * 4)  // u64[8][SELCAP]
#define TBOX_OFF   (SEL_OFF + (size_t)BIMG * SELCAP * 8)     // f32[8][2048][4]
#define TSB_OFF    (TBOX_OFF + (size_t)BIMG * KPRE * 16)     // f32[8][2048][4] shifted
#define TSC_OFF    (TSB_OFF + (size_t)BIMG * KPRE * 16)      // f32[8][2048]
#define TLB_OFF    (TSC_OFF + (size_t)BIMG * KPRE * 4)       // i32[8][2048]
#define TVL_OFF    (TLB_OFF + (size_t)BIMG * KPRE * 4)       // u32[8][2048]
#define KEEP_OFF   (TVL_OFF + (size_t)BIMG * KPRE * 4)       // u64[8][32]
#define MASK_OFF   (KEEP_OFF + (size_t)BIMG * 32 * 8)        // u64[8][2048][32]
#define CAND_OFF   (MASK_OFF + (size_t)BIMG * KPRE * 32 * 8) // u32[8][360000]
#define WS_NEED    (CAND_OFF + (size_t)BIMG * MCAND * 4)

__device__ __forceinline__ void decode_clip(const float4 rg, const float w, const float h,
                                            const float cx, const float cy,
                                            const float fw, const float fh, float bx[4]) {
    float dx = rg.x / 10.0f;
    float dy = rg.y / 10.0f;
    float dw = fminf(rg.z / 5.0f, BBOX_CLIP);
    float dh = fminf(rg.w / 5.0f, BBOX_CLIP);
    float pcx = dx * w + cx;
    float pcy = dy * h + cy;
    float pw  = expf(dw) * w;
    float phh = expf(dh) * h;
    bx[0] = fminf(fmaxf(pcx - 0.5f * pw,  0.0f), fw);
    bx[1] = fminf(fmaxf(pcy - 0.5f * phh, 0.0f), fh);
    bx[2] = fminf(fmaxf(pcx + 0.5f * pw,  0.0f), fw);
    bx[3] = fminf(fmaxf(pcy + 0.5f * phh, 0.0f), fh);
}

// K1: one wave per proposal row. Softmax(91), decode+clip 90 class boxes,
// validity mask; store order-preserving score bits (0 = invalid) and histogram
// valid candidates into 4096 buckets (top 12 bits of ord).
__global__ __launch_bounds__(256) void k1_score_hist(
    const float* __restrict__ logits, const float* __restrict__ reg,
    const float* __restrict__ props, const int* __restrict__ imh, const int* __restrict__ imw,
    u32* __restrict__ hist, u32* __restrict__ cand_ord) {
    const int lane = threadIdx.x & 63;
    const int pid = blockIdx.x * 4 + (threadIdx.x >> 6);
    if (pid >= BIMG * NPROP) return;
    const int img = pid / NPROP;
    const float fw = (float)imw[0], fh = (float)imh[0];
    const float* lrow = logits + (size_t)pid * NCLS;
    float v0 = lrow[lane];
    float v1 = (lane < 27) ? lrow[lane + 64] : -3.0e38f;
    float mx = fmaxf(v0, v1);
#pragma unroll
    for (int o = 32; o > 0; o >>= 1) mx = fmaxf(mx, __shfl_xor(mx, o));
    float es = expf(v0 - mx) + ((lane < 27) ? expf(v1 - mx) : 0.0f);
#pragma unroll
    for (int o = 32; o > 0; o >>= 1) es += __shfl_xor(es, o);
    float4 p = reinterpret_cast<const float4*>(props)[pid];
    const float w = p.z - p.x, h = p.w - p.y;
    const float cx = p.x + 0.5f * w, cy = p.y + 0.5f * h;
    const float4* rrow = reinterpret_cast<const float4*>(reg) + (size_t)pid * NCLS;
    u32* co = cand_ord + (size_t)img * MCAND + (size_t)(pid - img * NPROP) * CM1;
#pragma unroll
    for (int batch = 0; batch < 2; ++batch) {
        int ci = lane + batch * 64;
        if (ci < CM1) {
            int c = ci + 1;
            float sc = expf(lrow[c] - mx) / es;
            float4 rg = rrow[c];
            float bx[4];
            decode_clip(rg, w, h, cx, cy, fw, fh, bx);
            bool valid = (sc > SCORE_T) && (bx[2] - bx[0] >= 1.0f) && (bx[3] - bx[1] >= 1.0f);
            u32 o = 0u;
            if (valid) {
                o = __float_as_uint(sc) | 0x80000000u;  // sc > 0 always
                atomicAdd(&hist[img * NBUCKET + (o >> 20)], 1u);
            }
            co[ci] = o;
        }
    }
}

// K2: one wave per image. Reverse (descending-bucket) exclusive scan of the
// histogram -> start[], threshold bucket T straddling rank KPRE, V, fillneed.
__global__ __launch_bounds__(64) void k2_scan(
    const u32* __restrict__ hist, u32* __restrict__ start, u32* __restrict__ meta) {
    const int img = blockIdx.x;
    const int lane = threadIdx.x;
    u32 base = 0;
    int T = -1;
    for (int chunk = 63; chunk >= 0; --chunk) {
        int bucket = chunk * 64 + 63 - lane;   // lane order = descending bucket
        u32 cnt = hist[img * NBUCKET + bucket];
        u32 inc = cnt;
#pragma unroll
        for (int o = 1; o < 64; o <<= 1) {
            u32 t = __shfl_up(inc, o);
            if (lane >= o) inc += t;
        }
        u32 excl = base + inc - cnt;
        start[img * NBUCKET + bucket] = excl;
        bool cross = (cnt > 0) && (excl < KPRE) && (excl + cnt >= KPRE);
        u64 bal = __ballot(cross);
        if (T < 0 && bal != 0ull) {
            int l = __ffsll(bal) - 1;
            T = chunk * 64 + 63 - l;
        }
        base += __shfl(inc, 63);
    }
    if (lane == 0) {
        meta[img * 8 + 0] = base;                                  // V = total valid
        meta[img * 8 + 1] = (T >= 0) ? (u32)T : 0u;                // threshold bucket
        meta[img * 8 + 2] = (base < KPRE) ? (KPRE - base) : 0u;    // fill needed
    }
}

// K3: compact candidates in buckets >= T into sel[], placed at bucket-start +
// within-bucket atomic position. Key = ord<<32 | ~idx (desc value, asc index).
__global__ __launch_bounds__(256) void k3_compact(
    const u32* __restrict__ cand_ord, const u32* __restrict__ start,
    const u32* __restrict__ meta, u32* __restrict__ bcnt, u64* __restrict__ sel) {
    const u32 t = blockIdx.x * 256 + threadIdx.x;
    if (t >= (u32)(BIMG * MCAND)) return;
    const int img = t / MCAND;
    const u32 idx = t - (u32)img * MCAND;
    const u32 o = cand_ord[t];
    if (!o) return;
    const u32 bk = o >> 20;
    if (bk < meta[img * 8 + 1]) return;
    const u32 pos = start[img * NBUCKET + bk] + atomicAdd(&bcnt[img * NBUCKET + bk], 1u);
    if (pos < SELCAP)
        sel[(size_t)img * SELCAP + pos] = ((u64)o << 32) | (u32)(~idx);
}

// K3b: rare path — fewer than KPRE valid: fill remaining slots with invalid
// candidates (score -1) in ascending-index order (lax.top_k tie semantics).
__global__ __launch_bounds__(64) void k3b_fill(
    const u32* __restrict__ cand_ord, const u32* __restrict__ meta, u64* __restrict__ sel) {
    const int img = blockIdx.x;
    const u32 need = meta[img * 8 + 2];
    if (need == 0) return;
    const u32 V = meta[img * 8 + 0];
    const int lane = threadIdx.x;
    const u32 ORDN1 = 0x407FFFFFu;  // ord_of(-1.0f)
    u32 filled = 0;
    for (u32 b0 = 0; b0 < MCAND && filled < need; b0 += 64) {
        u32 idx = b0 + lane;
        bool inv = (idx < MCAND) && (cand_ord[(size_t)img * MCAND + idx] == 0u);
        u64 bal = __ballot(inv);
        u32 pre = (u32)__popcll(bal & ((1ull << lane) - 1ull));
        if (inv && (filled + pre) < need)
            sel[(size_t)img * SELCAP + V + filled + pre] = ((u64)ORDN1 << 32) | (u32)(~idx);
        filled += (u32)__popcll(bal);
    }
}

// K4: sort each compacted bucket segment (those intersecting the top-KPRE
// region) descending by key via LDS bitonic. Segments are disjoint and already
// in global descending-bucket order, so afterwards sel[0..2047] is the exact
// top-2048 in lax.top_k order.
__global__ __launch_bounds__(256) void k4_sortseg(
    const u32* __restrict__ hist, const u32* __restrict__ start, u64* __restrict__ sel) {
    __shared__ u64 arr[4096];
    const int img = blockIdx.y;
    const int tid = threadIdx.x;
    for (int bk = blockIdx.x * 16; bk < blockIdx.x * 16 + 16; ++bk) {
        u32 cnt = hist[img * NBUCKET + bk];          // uniform across block
        if (cnt < 2) continue;
        u32 st = start[img * NBUCKET + bk];
        if (st >= KPRE) continue;                    // below top region
        if (st + cnt > SELCAP) cnt = SELCAP - st;
        if (cnt > 4096) cnt = 4096;                  // pathological only
        int n = 1;
        while (n < (int)cnt) n <<= 1;
        u64* seg = sel + (size_t)img * SELCAP + st;
        for (int i = tid; i < n; i += 256) arr[i] = (i < (int)cnt) ? seg[i] : 0ull;
        __syncthreads();
        for (int k = 2; k <= n; k <<= 1)
            for (int j = k >> 1; j > 0; j >>= 1) {
                for (int i = tid; i < n; i += 256) {
                    int ixj = i ^ j;
                    if (ixj > i) {
                        u64 a = arr[i], b = arr[ixj];
                        bool swp = ((i & k) == 0) ? (a < b) : (a > b);
                        if (swp) { arr[i] = b; arr[ixj] = a; }
                    }
                }
                __syncthreads();
            }
        for (int i = tid; i < (int)cnt; i += 256) seg[i] = arr[i];
        __syncthreads();
    }
}

// K5: gather the top-2048: re-decode boxes, store score/label/valid, compute
// max coordinate and class-offset shifted boxes exactly as the reference.
__global__ __launch_bounds__(256) void k5_gather(
    const u64* __restrict__ sel, const float* __restrict__ reg, const float* __restrict__ props,
    const int* __restrict__ imh, const int* __restrict__ imw,
    float* __restrict__ tbox, float* __restrict__ tsb, float* __restrict__ tsc,
    int* __restrict__ tlb, u32* __restrict__ tvl) {
    const int img = blockIdx.x;
    const int tid = threadIdx.x;
    const float fw = (float)imw[0], fh = (float)imh[0];
    float bx[8][4];
    int lab[8];
    float lm = -3.0e38f;
#pragma unroll
    for (int t = 0; t < 8; ++t) {
        int s = t * 256 + tid;
        u64 key = sel[(size_t)img * SELCAP + s];
        u32 o = (u32)(key >> 32);
        u32 idx = ~((u32)key);
        u32 b = (o & 0x80000000u) ? (o & 0x7FFFFFFFu) : ~o;
        float sc = __uint_as_float(b);               // exact masked score roundtrip
        u32 n = idx / CM1;
        int c = (int)(idx - n * CM1) + 1;
        int pid = img * NPROP + (int)n;
        float4 p = reinterpret_cast<const float4*>(props)[pid];
        float w = p.z - p.x, h = p.w - p.y;
        float cx = p.x + 0.5f * w, cy = p.y + 0.5f * h;
        float4 rg = reinterpret_cast<const float4*>(reg)[(size_t)pid * NCLS + c];
        decode_clip(rg, w, h, cx, cy, fw, fh, bx[t]);
        lab[t] = c;
        lm = fmaxf(lm, fmaxf(fmaxf(bx[t][0], bx[t][1]), fmaxf(bx[t][2], bx[t][3])));
        reinterpret_cast<float4*>(tbox)[(size_t)img * KPRE + s] =
            make_float4(bx[t][0], bx[t][1], bx[t][2], bx[t][3]);
        tsc[(size_t)img * KPRE + s] = sc;
        tlb[(size_t)img * KPRE + s] = c;
        tvl[(size_t)img * KPRE + s] = (sc > SCORE_T) ? 1u : 0u;
    }
#pragma unroll
    for (int o2 = 32; o2 > 0; o2 >>= 1) lm = fmaxf(lm, __shfl_xor(lm, o2));
    __shared__ float wm[4];
    if ((tid & 63) == 0) wm[tid >> 6] = lm;
    __syncthreads();
    float mplus = fmaxf(fmaxf(wm[0], wm[1]), fmaxf(wm[2], wm[3])) + 1.0f;
#pragma unroll
    for (int t = 0; t < 8; ++t) {
        int s = t * 256 + tid;
        float off = (float)lab[t] * mplus;
        reinterpret_cast<float4*>(tsb)[(size_t)img * KPRE + s] =
            make_float4(bx[t][0] + off, bx[t][1] + off, bx[t][2] + off, bx[t][3] + off);
    }
}

// K6: suppression bitmask. Block = 64 rows x 64 cols; bit set iff
// iou(shifted_i, shifted_j) > thresh and j > i (reference formula verbatim).
__global__ __launch_bounds__(64) void k6_mask(
    const float* __restrict__ tsb, u64* __restrict__ mask) {
    const int img = blockIdx.z;
    const int j0 = blockIdx.x * 64;
    const int i0 = blockIdx.y * 64;
    const int tid = threadIdx.x;
    __shared__ float4 cb[64];
    __shared__ float ca[64];
    float4 c = reinterpret_cast<const float4*>(tsb)[(size_t)img * KPRE + j0 + tid];
    cb[tid] = c;
    ca[tid] = (c.z - c.x) * (c.w - c.y);
    __syncthreads();
    const int i = i0 + tid;
    float4 r = reinterpret_cast<const float4*>(tsb)[(size_t)img * KPRE + i];
    float ra = (r.z - r.x) * (r.w - r.y);
    u64 bits = 0ull;
#pragma unroll 8
    for (int jj = 0; jj < 64; ++jj) {
        int j = j0 + jj;
        float4 cc = cb[jj];
        float wv = fmaxf(fminf(r.z, cc.z) - fmaxf(r.x, cc.x), 0.0f);
        float hv = fmaxf(fminf(r.w, cc.w) - fmaxf(r.y, cc.y), 0.0f);
        float inter = wv * hv;
        float iou = inter / ((ra + ca[jj]) - inter);   // NaN compares false, like jnp
        if ((iou > NMS_T) && (j > i)) bits |= (1ull << jj);
    }
    mask[((size_t)img * KPRE + i) * 32 + (j0 >> 6)] = bits;
}

// ---- K7 v3: greedy scan with an all-scalar serial chain ----
// One wave per image. Per 64-row block:
//   serial: A (SGPR u64) over 64 unrolled steps; row words come from a
//           prefetched VGPR pair via v_readlane (constant lane, off-chain).
//   apply:  kept rows' full 32-word masks OR into lane-distributed 'removed'
//           (lanes 0-31 = half A, lanes 32-63 = replicated half B; each
//           512B load covers 2 rows; 32 NAMED registers via macros — no
//           indexed private arrays, no scratch).
__device__ __forceinline__ u64 rdlane64(u64 v, int l) {
    u32 lo = (u32)__builtin_amdgcn_readlane((int)(u32)v, l);
    u32 hi = (u32)__builtin_amdgcn_readlane((int)(u32)(v >> 32), l);
    return ((u64)hi << 32) | lo;
}

#define REP32(M) M(0) M(1) M(2) M(3) M(4) M(5) M(6) M(7) M(8) M(9) M(10) M(11) \
    M(12) M(13) M(14) M(15) M(16) M(17) M(18) M(19) M(20) M(21) M(22) M(23)   \
    M(24) M(25) M(26) M(27) M(28) M(29) M(30) M(31)

__global__ __launch_bounds__(64) void k7_nms(
    const u64* __restrict__ mask, const u32* __restrict__ tvl, u64* __restrict__ keepw) {
    const int img = blockIdx.x;
    const int lane = threadIdx.x;
    const int half = lane >> 5;          // 0: half A, 1: half B
    const u64* mrow = mask + (size_t)img * KPRE * 32;

    // removed: lane l<32 holds partial word l (half A); lanes 32-63 partial
    // word l-32 (half B). Invalid rows pre-removed into half A.
    u64 removed = 0ull;
    for (int w = 0; w < 32; ++w) {
        bool tv = tvl[(size_t)img * KPRE + w * 64 + lane] != 0u;
        u64 bal = __ballot(tv);
        if (lane == w) removed = ~bal;
    }

    // diag word for block 0: lane u holds mask[(u)*32 + 0]
    u64 diag = mrow[(size_t)lane * 32];
    u64 rp = rdlane64(removed, 0) | rdlane64(removed, 32);   // seed word 0

    for (int b = 0; b < 32; ++b) {
        const size_t base32 = (size_t)b * 2048;   // (64*b)*32 u64s

        // prefetch next block's diagonal words first (longest-lived load)
        u64 diagn = 0ull;
        if (b + 1 < 32)
            diagn = mrow[base32 + 2048 + (size_t)lane * 32 + (b + 1)];

        // issue this block's application rows: load g covers rows 2g (lanes
        // 0-31) and 2g+1 (lanes 32-63); index = base32 + 64g + lane.
#define AP_LOAD(g) u64 ap##g = mrow[base32 + 64 * (g) + lane];
        REP32(AP_LOAD)
#undef AP_LOAD

        // serial in-block phase: pure scalar recurrence (covers load latency)
        u64 A = rp;
#pragma unroll
        for (int u = 0; u < 64; ++u) {
            u64 row = rdlane64(diag, u);
            if (!((A >> u) & 1ull)) A |= row;      // row has only bits > u
        }
        const u64 keptw = ~A;

        // apply kept rows to distributed removed (predicate per half)
#define AP_APPLY(g) removed |= (((keptw >> (2 * (g) + half)) & 1ull) ? ap##g : 0ull);
        REP32(AP_APPLY)
#undef AP_APPLY

        // seed word for next block (after application)
        const int nb = (b + 1) & 31;
        rp = rdlane64(removed, nb) | rdlane64(removed, 32 + nb);
        diag = diagn;
    }

    // merge the two halves and emit keep words
    removed |= __shfl_xor(removed, 32);
    if (lane < 32) keepw[img * 32 + lane] = ~removed;
}

// K8: final top-100 per image (bitonic over 2048 keys) + output writes.
__global__ __launch_bounds__(256) void k8_final(
    const u64* __restrict__ keepw, const float* __restrict__ tsc,
    const float* __restrict__ tbox, const int* __restrict__ tlb,
    float* __restrict__ out) {
    __shared__ u64 arr[KPRE];
    const int img = blockIdx.x;
    const int tid = threadIdx.x;
#pragma unroll
    for (int t = 0; t < 8; ++t) {
        int s = t * 256 + tid;
        u64 kw = keepw[img * 32 + (s >> 6)];
        bool kept = (kw >> (s & 63)) & 1ull;
        float ks = kept ? tsc[(size_t)img * KPRE + s] : -1.0f;
        u32 b = __float_as_uint(ks);
        u32 o = (b & 0x80000000u) ? ~b : (b | 0x80000000u);
        arr[s] = ((u64)o << 32) | (u32)(~(u32)s);
    }
    __syncthreads();
    for (int k = 2; k <= KPRE; k <<= 1)
        for (int j = k >> 1; j > 0; j >>= 1) {
            for (int i = tid; i < KPRE; i += 256) {
                int ixj = i ^ j;
                if (ixj > i) {
                    u64 a = arr[i], bb = arr[ixj];
                    bool swp = ((i & k) == 0) ? (a < bb) : (a > bb);
                    if (swp) { arr[i] = bb; arr[ixj] = a; }
                }
            }
            __syncthreads();
        }
    if (tid < DETS) {
        u64 key = arr[tid];
        u32 o = (u32)(key >> 32);
        u32 b = (o & 0x80000000u) ? (o & 0x7FFFFFFFu) : ~o;
        float fs = __uint_as_float(b);
        u32 s = ~((u32)key);
        bool fv = fs > SCORE_T;
        float4 bxv = make_float4(0.0f, 0.0f, 0.0f, 0.0f);
        float lb = -1.0f, scw = 0.0f;
        if (fv) {
            bxv = reinterpret_cast<const float4*>(tbox)[(size_t)img * KPRE + s];
            lb = (float)tlb[(size_t)img * KPRE + s];
            scw = fs;
        }
        float* ob = out + (size_t)img * DETS * 4 + (size_t)tid * 4;
        ob[0] = bxv.x; ob[1] = bxv.y; ob[2] = bxv.z; ob[3] = bxv.w;
        out[BIMG * DETS * 4 + img * DETS + tid] = scw;   // scores at 3200
        out[BIMG * DETS * 5 + img * DETS + tid] = lb;    // labels at 4000
    }
}

extern "C" void kernel_launch(void* const* d_in, const int* in_sizes, int n_in,
                              void* d_out, int out_size, void* d_ws, size_t ws_size,
                              hipStream_t stream) {
    const float* logits = (const float*)d_in[0];
    const float* reg    = (const float*)d_in[1];
    const float* props  = (const float*)d_in[2];
    const int*   imh    = (const int*)d_in[3];
    const int*   imw    = (const int*)d_in[4];
    float* out = (float*)d_out;
    char* ws = (char*)d_ws;
    if (ws_size < WS_NEED) return;  // ~17.1 MB needed

    u32* hist = (u32*)(ws + HIST_OFF);
    u32* bcnt = (u32*)(ws + BCNT_OFF);
    u32* meta = (u32*)(ws + META_OFF);
    u32* start = (u32*)(ws + START_OFF);
    u64* sel  = (u64*)(ws + SEL_OFF);
    float* tbox = (float*)(ws + TBOX_OFF);
    float* tsb  = (float*)(ws + TSB_OFF);
    float* tsc  = (float*)(ws + TSC_OFF);
    int*   tlb  = (int*)(ws + TLB_OFF);
    u32*   tvl  = (u32*)(ws + TVL_OFF);
    u64*   keepw = (u64*)(ws + KEEP_OFF);
    u64*   mask = (u64*)(ws + MASK_OFF);
    u32*   cand_ord = (u32*)(ws + CAND_OFF);

    hipMemsetAsync(d_ws, 0, ZERO_BYTES, stream);  // hist, bcnt, meta

    k1_score_hist<<<BIMG * NPROP / 4, 256, 0, stream>>>(logits, reg, props, imh, imw,
                                                        hist, cand_ord);
    k2_scan<<<BIMG, 64, 0, stream>>>(hist, start, meta);
    k3_compact<<<(BIMG * MCAND) / 256, 256, 0, stream>>>(cand_ord, start, meta, bcnt, sel);
    k3b_fill<<<BIMG, 64, 0, stream>>>(cand_ord, meta, sel);
    k4_sortseg<<<dim3(256, BIMG), 256, 0, stream>>>(hist, start, sel);
    k5_gather<<<BIMG, 256, 0, stream>>>(sel, reg, props, imh, imw, tbox, tsb, tsc, tlb, tvl);
    k6_mask<<<dim3(32, 32, BIMG), 64, 0, stream>>>(tsb, mask);
    k7_nms<<<BIMG, 64, 0, stream>>>(mask, tvl, keepw);
    k8_final<<<BIMG, 256, 0, stream>>>(keepw, tsc, tbox, tlb, out);
}

// Round 4
// 483.102 us; speedup vs baseline: 1.8851x; 1.2121x over previous
//
#include <hip/hip_runtime.h>
#include <stdint.h>

typedef unsigned int u32;
typedef unsigned long long u64;

#define BIMG 8
#define NPROP 4000
#define NCLS 91
#define CM1 90
#define MCAND (NPROP * CM1)      // 360000 candidates per image
#define KPRE 2048
#define NBUCKET 4096
#define NREP 8                   // counter replicas (contention /8)
#define SELCAP 16384
#define DETS 100
#define SCORE_T 0.05f
#define NMS_T 0.5f
#define BBOX_CLIP 4.135166556742356f   // log(1000/16)

// ---------------- workspace layout ----------------
// zeroed region first: histrep + bcntrep + meta
#define HISTREP_OFF ((size_t)0)                                  // u32[8][8][4096] rep-major
#define BCNTREP_OFF (HISTREP_OFF + (size_t)NREP * BIMG * NBUCKET * 4)
#define META_OFF    (BCNTREP_OFF + (size_t)NREP * BIMG * NBUCKET * 4)  // u32[8][8]
#define ZERO_BYTES  (META_OFF + 4096)
#define START_OFF   (ZERO_BYTES)                                 // u32[8][4096]
#define HISTTOT_OFF (START_OFF + (size_t)BIMG * NBUCKET * 4)     // u32[8][4096]
#define STARTREP_OFF (HISTTOT_OFF + (size_t)BIMG * NBUCKET * 4)  // u32[8][8][4096]
#define SEL_OFF     (STARTREP_OFF + (size_t)NREP * BIMG * NBUCKET * 4) // u64[8][SELCAP]
#define TBOX_OFF    (SEL_OFF + (size_t)BIMG * SELCAP * 8)        // f32[8][2048][4]
#define TSB_OFF     (TBOX_OFF + (size_t)BIMG * KPRE * 16)        // f32[8][2048][4]
#define TSC_OFF     (TSB_OFF + (size_t)BIMG * KPRE * 16)         // f32[8][2048]
#define TLB_OFF     (TSC_OFF + (size_t)BIMG * KPRE * 4)          // i32[8][2048]
#define TVL_OFF     (TLB_OFF + (size_t)BIMG * KPRE * 4)          // u32[8][2048]
#define KEEP_OFF    (TVL_OFF + (size_t)BIMG * KPRE * 4)          // u64[8][32]
// UNION: cand_ord (u32[8][360000], dead after k3b) overlays mask
// (u64[8][2048][32], first written by k6). Same stream => ordered.
#define UNION_OFF   (KEEP_OFF + (size_t)BIMG * 32 * 8)
#define UNION_BYTES ((size_t)BIMG * MCAND * 4)                   // 11.52 MB > mask's 4 MB
#define WS_NEED     (UNION_OFF + UNION_BYTES)                    // ~16.7 MB

__device__ __forceinline__ void decode_clip(const float4 rg, const float w, const float h,
                                            const float cx, const float cy,
                                            const float fw, const float fh, float bx[4]) {
    float dx = rg.x / 10.0f;
    float dy = rg.y / 10.0f;
    float dw = fminf(rg.z / 5.0f, BBOX_CLIP);
    float dh = fminf(rg.w / 5.0f, BBOX_CLIP);
    float pcx = dx * w + cx;
    float pcy = dy * h + cy;
    float pw  = expf(dw) * w;
    float phh = expf(dh) * h;
    bx[0] = fminf(fmaxf(pcx - 0.5f * pw,  0.0f), fw);
    bx[1] = fminf(fmaxf(pcy - 0.5f * phh, 0.0f), fh);
    bx[2] = fminf(fmaxf(pcx + 0.5f * pw,  0.0f), fw);
    bx[3] = fminf(fmaxf(pcy + 0.5f * phh, 0.0f), fh);
}

// K1: one wave per proposal row. Softmax(91); conservative logit-space
// prefilter (l - mx > ln(es) + ln(0.05) - 1e-3) gates the expensive
// decode+divide path; passing lanes re-test exactly (bit-identical results).
// Histogram atomics go to NREP replicas keyed by (cand_idx>>8)&7 == the
// blockIdx of k3's thread covering that candidate.
__global__ __launch_bounds__(256) void k1_score_hist(
    const float* __restrict__ logits, const float* __restrict__ reg,
    const float* __restrict__ props, const int* __restrict__ imh, const int* __restrict__ imw,
    u32* __restrict__ histrep, u32* __restrict__ cand_ord) {
    const int lane = threadIdx.x & 63;
    const int pid = blockIdx.x * 4 + (threadIdx.x >> 6);
    if (pid >= BIMG * NPROP) return;
    const int img = pid / NPROP;
    const float fw = (float)imw[0], fh = (float)imh[0];
    const float* lrow = logits + (size_t)pid * NCLS;
    float v0 = lrow[lane];
    float v1 = (lane < 27) ? lrow[lane + 64] : -3.0e38f;
    float mx = fmaxf(v0, v1);
#pragma unroll
    for (int o = 32; o > 0; o >>= 1) mx = fmaxf(mx, __shfl_xor(mx, o));
    float es = expf(v0 - mx) + ((lane < 27) ? expf(v1 - mx) : 0.0f);
#pragma unroll
    for (int o = 32; o > 0; o >>= 1) es += __shfl_xor(es, o);
    const float thr = mx + logf(es) - 2.9967323f;   // ln(0.05) - 1e-3 margin
    float4 p = reinterpret_cast<const float4*>(props)[pid];
    const float w = p.z - p.x, h = p.w - p.y;
    const float cx = p.x + 0.5f * w, cy = p.y + 0.5f * h;
    const float4* rrow = reinterpret_cast<const float4*>(reg) + (size_t)pid * NCLS;
    const int n = pid - img * NPROP;
    u32* co = cand_ord + (size_t)img * MCAND + (size_t)n * CM1;
#pragma unroll
    for (int batch = 0; batch < 2; ++batch) {
        int ci = lane + batch * 64;
        if (ci < CM1) {
            int c = ci + 1;
            float l = lrow[c];
            u32 o = 0u;
            if (l > thr) {                        // rare (~2% of lanes)
                float sc = expf(l - mx) / es;     // exact, same as before
                float4 rg = rrow[c];
                float bx[4];
                decode_clip(rg, w, h, cx, cy, fw, fh, bx);
                bool valid = (sc > SCORE_T) && (bx[2] - bx[0] >= 1.0f) && (bx[3] - bx[1] >= 1.0f);
                if (valid) {
                    o = __float_as_uint(sc) | 0x80000000u;  // sc > 0 always
                    u32 t = (u32)img * MCAND + (u32)n * CM1 + (u32)ci;
                    int rep = (int)((t >> 8) & (NREP - 1));
                    atomicAdd(&histrep[((size_t)rep * BIMG + img) * NBUCKET + (o >> 20)], 1u);
                }
            }
            co[ci] = o;
        }
    }
}

// K2: one 256-thread block per image. Sums the NREP histogram replicas,
// block-scans in descending-bucket order -> start[], per-rep sub-offsets
// startrep[], summed histtot[] (for k4), threshold bucket T, V, fillneed.
__global__ __launch_bounds__(256) void k2_scan(
    const u32* __restrict__ histrep, u32* __restrict__ histtot,
    u32* __restrict__ start, u32* __restrict__ startrep, u32* __restrict__ meta) {
    const int img = blockIdx.x;
    const int td = threadIdx.x;
    const int lane = td & 63, wv = td >> 6;
    u32 cnt[16]; u32 tsum = 0;
#pragma unroll
    for (int k = 0; k < 16; ++k) {
        const int bk = NBUCKET - 1 - (td * 16 + k);
        u32 c = 0;
#pragma unroll
        for (int r = 0; r < NREP; ++r)
            c += histrep[((size_t)r * BIMG + img) * NBUCKET + bk];
        cnt[k] = c; tsum += c;
    }
    u32 inc = tsum;
#pragma unroll
    for (int o = 1; o < 64; o <<= 1) { u32 t = __shfl_up(inc, o); if (lane >= o) inc += t; }
    __shared__ u32 wsum[4];
    __shared__ u32 TbkS, Vs;
    if (td == 0) TbkS = 0u;
    if (lane == 63) wsum[wv] = inc;
    __syncthreads();
    u32 wbase = 0;
    for (int i = 0; i < wv; ++i) wbase += wsum[i];
    if (td == 255) Vs = wbase + inc;
    u32 excl = wbase + inc - tsum;
#pragma unroll
    for (int k = 0; k < 16; ++k) {
        const int bk = NBUCKET - 1 - (td * 16 + k);
        const u32 c = cnt[k];
        start[img * NBUCKET + bk] = excl;
        histtot[img * NBUCKET + bk] = c;
        u32 sub = excl;
#pragma unroll
        for (int r = 0; r < NREP; ++r) {
            startrep[((size_t)r * BIMG + img) * NBUCKET + bk] = sub;
            sub += histrep[((size_t)r * BIMG + img) * NBUCKET + bk];
        }
        if (c > 0 && excl < KPRE && excl + c >= KPRE) TbkS = (u32)bk;  // <=1 writer
        excl += c;
    }
    __syncthreads();
    if (td == 0) {
        u32 V = Vs;
        meta[img * 8 + 0] = V;
        meta[img * 8 + 1] = TbkS;
        meta[img * 8 + 2] = (V < KPRE) ? (KPRE - V) : 0u;
    }
}

// K3: compact candidates in buckets >= T into sel[], position = per-rep
// sub-range start + per-rep atomic counter (rep = blockIdx & 7, contention /8).
// Within-bucket order is arbitrary — k4 sorts the whole segment by key.
__global__ __launch_bounds__(256) void k3_compact(
    const u32* __restrict__ cand_ord, const u32* __restrict__ startrep,
    const u32* __restrict__ meta, u32* __restrict__ bcntrep, u64* __restrict__ sel) {
    const u32 t = blockIdx.x * 256 + threadIdx.x;
    const int rep = (int)(blockIdx.x & (NREP - 1));   // == (t>>8)&7
    if (t >= (u32)(BIMG * MCAND)) return;
    const int img = t / MCAND;
    const u32 idx = t - (u32)img * MCAND;
    const u32 o = cand_ord[t];
    if (!o) return;
    const u32 bk = o >> 20;
    if (bk < meta[img * 8 + 1]) return;
    const size_t ri = ((size_t)rep * BIMG + img) * NBUCKET + bk;
    const u32 pos = startrep[ri] + atomicAdd(&bcntrep[ri], 1u);
    if (pos < SELCAP)
        sel[(size_t)img * SELCAP + pos] = ((u64)o << 32) | (u32)(~idx);
}

// K3b: rare path — fewer than KPRE valid: fill remaining slots with invalid
// candidates (score -1) in ascending-index order (lax.top_k tie semantics).
__global__ __launch_bounds__(64) void k3b_fill(
    const u32* __restrict__ cand_ord, const u32* __restrict__ meta, u64* __restrict__ sel) {
    const int img = blockIdx.x;
    const u32 need = meta[img * 8 + 2];
    if (need == 0) return;
    const u32 V = meta[img * 8 + 0];
    const int lane = threadIdx.x;
    const u32 ORDN1 = 0x407FFFFFu;  // ord_of(-1.0f)
    u32 filled = 0;
    for (u32 b0 = 0; b0 < MCAND && filled < need; b0 += 64) {
        u32 idx = b0 + lane;
        bool inv = (idx < MCAND) && (cand_ord[(size_t)img * MCAND + idx] == 0u);
        u64 bal = __ballot(inv);
        u32 pre = (u32)__popcll(bal & ((1ull << lane) - 1ull));
        if (inv && (filled + pre) < need)
            sel[(size_t)img * SELCAP + V + filled + pre] = ((u64)ORDN1 << 32) | (u32)(~idx);
        filled += (u32)__popcll(bal);
    }
}

// K4: sort each compacted bucket segment (those intersecting the top-KPRE
// region) descending by key via LDS bitonic.
__global__ __launch_bounds__(256) void k4_sortseg(
    const u32* __restrict__ histtot, const u32* __restrict__ start, u64* __restrict__ sel) {
    __shared__ u64 arr[4096];
    const int img = blockIdx.y;
    const int tid = threadIdx.x;
    for (int bk = blockIdx.x * 16; bk < blockIdx.x * 16 + 16; ++bk) {
        u32 cnt = histtot[img * NBUCKET + bk];       // uniform across block
        if (cnt < 2) continue;
        u32 st = start[img * NBUCKET + bk];
        if (st >= KPRE) continue;                    // below top region
        if (st + cnt > SELCAP) cnt = SELCAP - st;
        if (cnt > 4096) cnt = 4096;                  // pathological only
        int n = 1;
        while (n < (int)cnt) n <<= 1;
        u64* seg = sel + (size_t)img * SELCAP + st;
        for (int i = tid; i < n; i += 256) arr[i] = (i < (int)cnt) ? seg[i] : 0ull;
        __syncthreads();
        for (int k = 2; k <= n; k <<= 1)
            for (int j = k >> 1; j > 0; j >>= 1) {
                for (int i = tid; i < n; i += 256) {
                    int ixj = i ^ j;
                    if (ixj > i) {
                        u64 a = arr[i], b = arr[ixj];
                        bool swp = ((i & k) == 0) ? (a < b) : (a > b);
                        if (swp) { arr[i] = b; arr[ixj] = a; }
                    }
                }
                __syncthreads();
            }
        for (int i = tid; i < (int)cnt; i += 256) seg[i] = arr[i];
        __syncthreads();
    }
}

// K5: gather the top-2048: re-decode boxes, store score/label/valid, compute
// max coordinate and class-offset shifted boxes exactly as the reference.
__global__ __launch_bounds__(256) void k5_gather(
    const u64* __restrict__ sel, const float* __restrict__ reg, const float* __restrict__ props,
    const int* __restrict__ imh, const int* __restrict__ imw,
    float* __restrict__ tbox, float* __restrict__ tsb, float* __restrict__ tsc,
    int* __restrict__ tlb, u32* __restrict__ tvl) {
    const int img = blockIdx.x;
    const int tid = threadIdx.x;
    const float fw = (float)imw[0], fh = (float)imh[0];
    float bx[8][4];
    int lab[8];
    float lm = -3.0e38f;
#pragma unroll
    for (int t = 0; t < 8; ++t) {
        int s = t * 256 + tid;
        u64 key = sel[(size_t)img * SELCAP + s];
        u32 o = (u32)(key >> 32);
        u32 idx = ~((u32)key);
        u32 b = (o & 0x80000000u) ? (o & 0x7FFFFFFFu) : ~o;
        float sc = __uint_as_float(b);               // exact masked score roundtrip
        u32 n = idx / CM1;
        int c = (int)(idx - n * CM1) + 1;
        int pid = img * NPROP + (int)n;
        float4 p = reinterpret_cast<const float4*>(props)[pid];
        float w = p.z - p.x, h = p.w - p.y;
        float cx = p.x + 0.5f * w, cy = p.y + 0.5f * h;
        float4 rg = reinterpret_cast<const float4*>(reg)[(size_t)pid * NCLS + c];
        decode_clip(rg, w, h, cx, cy, fw, fh, bx[t]);
        lab[t] = c;
        lm = fmaxf(lm, fmaxf(fmaxf(bx[t][0], bx[t][1]), fmaxf(bx[t][2], bx[t][3])));
        reinterpret_cast<float4*>(tbox)[(size_t)img * KPRE + s] =
            make_float4(bx[t][0], bx[t][1], bx[t][2], bx[t][3]);
        tsc[(size_t)img * KPRE + s] = sc;
        tlb[(size_t)img * KPRE + s] = c;
        tvl[(size_t)img * KPRE + s] = (sc > SCORE_T) ? 1u : 0u;
    }
#pragma unroll
    for (int o2 = 32; o2 > 0; o2 >>= 1) lm = fmaxf(lm, __shfl_xor(lm, o2));
    __shared__ float wm[4];
    if ((tid & 63) == 0) wm[tid >> 6] = lm;
    __syncthreads();
    float mplus = fmaxf(fmaxf(wm[0], wm[1]), fmaxf(wm[2], wm[3])) + 1.0f;
#pragma unroll
    for (int t = 0; t < 8; ++t) {
        int s = t * 256 + tid;
        float off = (float)lab[t] * mplus;
        reinterpret_cast<float4*>(tsb)[(size_t)img * KPRE + s] =
            make_float4(bx[t][0] + off, bx[t][1] + off, bx[t][2] + off, bx[t][3] + off);
    }
}

// K6: suppression bitmask. Block = 64 rows x 64 cols; bit set iff
// iou(shifted_i, shifted_j) > thresh and j > i (reference formula verbatim).
__global__ __launch_bounds__(64) void k6_mask(
    const float* __restrict__ tsb, u64* __restrict__ mask) {
    const int img = blockIdx.z;
    const int j0 = blockIdx.x * 64;
    const int i0 = blockIdx.y * 64;
    const int tid = threadIdx.x;
    __shared__ float4 cb[64];
    __shared__ float ca[64];
    float4 c = reinterpret_cast<const float4*>(tsb)[(size_t)img * KPRE + j0 + tid];
    cb[tid] = c;
    ca[tid] = (c.z - c.x) * (c.w - c.y);
    __syncthreads();
    const int i = i0 + tid;
    float4 r = reinterpret_cast<const float4*>(tsb)[(size_t)img * KPRE + i];
    float ra = (r.z - r.x) * (r.w - r.y);
    u64 bits = 0ull;
#pragma unroll 8
    for (int jj = 0; jj < 64; ++jj) {
        int j = j0 + jj;
        float4 cc = cb[jj];
        float wv = fmaxf(fminf(r.z, cc.z) - fmaxf(r.x, cc.x), 0.0f);
        float hv = fmaxf(fminf(r.w, cc.w) - fmaxf(r.y, cc.y), 0.0f);
        float inter = wv * hv;
        float iou = inter / ((ra + ca[jj]) - inter);   // NaN compares false, like jnp
        if ((iou > NMS_T) && (j > i)) bits |= (1ull << jj);
    }
    mask[((size_t)img * KPRE + i) * 32 + (j0 >> 6)] = bits;
}

// K7: greedy scan with an all-scalar serial chain (see r3 notes).
__device__ __forceinline__ u64 rdlane64(u64 v, int l) {
    u32 lo = (u32)__builtin_amdgcn_readlane((int)(u32)v, l);
    u32 hi = (u32)__builtin_amdgcn_readlane((int)(u32)(v >> 32), l);
    return ((u64)hi << 32) | lo;
}

#define REP32(M) M(0) M(1) M(2) M(3) M(4) M(5) M(6) M(7) M(8) M(9) M(10) M(11) \
    M(12) M(13) M(14) M(15) M(16) M(17) M(18) M(19) M(20) M(21) M(22) M(23)   \
    M(24) M(25) M(26) M(27) M(28) M(29) M(30) M(31)

__global__ __launch_bounds__(64) void k7_nms(
    const u64* __restrict__ mask, const u32* __restrict__ tvl, u64* __restrict__ keepw) {
    const int img = blockIdx.x;
    const int lane = threadIdx.x;
    const int half = lane >> 5;          // 0: half A, 1: half B
    const u64* mrow = mask + (size_t)img * KPRE * 32;

    u64 removed = 0ull;
    for (int w = 0; w < 32; ++w) {
        bool tv = tvl[(size_t)img * KPRE + w * 64 + lane] != 0u;
        u64 bal = __ballot(tv);
        if (lane == w) removed = ~bal;
    }

    u64 diag = mrow[(size_t)lane * 32];
    u64 rp = rdlane64(removed, 0) | rdlane64(removed, 32);

    for (int b = 0; b < 32; ++b) {
        const size_t base32 = (size_t)b * 2048;

        u64 diagn = 0ull;
        if (b + 1 < 32)
            diagn = mrow[base32 + 2048 + (size_t)lane * 32 + (b + 1)];

#define AP_LOAD(g) u64 ap##g = mrow[base32 + 64 * (g) + lane];
        REP32(AP_LOAD)
#undef AP_LOAD

        u64 A = rp;
#pragma unroll
        for (int u = 0; u < 64; ++u) {
            u64 row = rdlane64(diag, u);
            if (!((A >> u) & 1ull)) A |= row;
        }
        const u64 keptw = ~A;

#define AP_APPLY(g) removed |= (((keptw >> (2 * (g) + half)) & 1ull) ? ap##g : 0ull);
        REP32(AP_APPLY)
#undef AP_APPLY

        const int nb = (b + 1) & 31;
        rp = rdlane64(removed, nb) | rdlane64(removed, 32 + nb);
        diag = diagn;
    }

    removed |= __shfl_xor(removed, 32);
    if (lane < 32) keepw[img * 32 + lane] = ~removed;
}

// K8: final top-100 per image (bitonic over 2048 keys) + output writes.
__global__ __launch_bounds__(256) void k8_final(
    const u64* __restrict__ keepw, const float* __restrict__ tsc,
    const float* __restrict__ tbox, const int* __restrict__ tlb,
    float* __restrict__ out) {
    __shared__ u64 arr[KPRE];
    const int img = blockIdx.x;
    const int tid = threadIdx.x;
#pragma unroll
    for (int t = 0; t < 8; ++t) {
        int s = t * 256 + tid;
        u64 kw = keepw[img * 32 + (s >> 6)];
        bool kept = (kw >> (s & 63)) & 1ull;
        float ks = kept ? tsc[(size_t)img * KPRE + s] : -1.0f;
        u32 b = __float_as_uint(ks);
        u32 o = (b & 0x80000000u) ? ~b : (b | 0x80000000u);
        arr[s] = ((u64)o << 32) | (u32)(~(u32)s);
    }
    __syncthreads();
    for (int k = 2; k <= KPRE; k <<= 1)
        for (int j = k >> 1; j > 0; j >>= 1) {
            for (int i = tid; i < KPRE; i += 256) {
                int ixj = i ^ j;
                if (ixj > i) {
                    u64 a = arr[i], bb = arr[ixj];
                    bool swp = ((i & k) == 0) ? (a < bb) : (a > bb);
                    if (swp) { arr[i] = bb; arr[ixj] = a; }
                }
            }
            __syncthreads();
        }
    if (tid < DETS) {
        u64 key = arr[tid];
        u32 o = (u32)(key >> 32);
        u32 b = (o & 0x80000000u) ? (o & 0x7FFFFFFFu) : ~o;
        float fs = __uint_as_float(b);
        u32 s = ~((u32)key);
        bool fv = fs > SCORE_T;
        float4 bxv = make_float4(0.0f, 0.0f, 0.0f, 0.0f);
        float lb = -1.0f, scw = 0.0f;
        if (fv) {
            bxv = reinterpret_cast<const float4*>(tbox)[(size_t)img * KPRE + s];
            lb = (float)tlb[(size_t)img * KPRE + s];
            scw = fs;
        }
        float* ob = out + (size_t)img * DETS * 4 + (size_t)tid * 4;
        ob[0] = bxv.x; ob[1] = bxv.y; ob[2] = bxv.z; ob[3] = bxv.w;
        out[BIMG * DETS * 4 + img * DETS + tid] = scw;   // scores at 3200
        out[BIMG * DETS * 5 + img * DETS + tid] = lb;    // labels at 4000
    }
}

extern "C" void kernel_launch(void* const* d_in, const int* in_sizes, int n_in,
                              void* d_out, int out_size, void* d_ws, size_t ws_size,
                              hipStream_t stream) {
    const float* logits = (const float*)d_in[0];
    const float* reg    = (const float*)d_in[1];
    const float* props  = (const float*)d_in[2];
    const int*   imh    = (const int*)d_in[3];
    const int*   imw    = (const int*)d_in[4];
    float* out = (float*)d_out;
    char* ws = (char*)d_ws;
    if (ws_size < WS_NEED) return;  // ~16.7 MB needed

    u32* histrep  = (u32*)(ws + HISTREP_OFF);
    u32* bcntrep  = (u32*)(ws + BCNTREP_OFF);
    u32* meta     = (u32*)(ws + META_OFF);
    u32* start    = (u32*)(ws + START_OFF);
    u32* histtot  = (u32*)(ws + HISTTOT_OFF);
    u32* startrep = (u32*)(ws + STARTREP_OFF);
    u64* sel  = (u64*)(ws + SEL_OFF);
    float* tbox = (float*)(ws + TBOX_OFF);
    float* tsb  = (float*)(ws + TSB_OFF);
    float* tsc  = (float*)(ws + TSC_OFF);
    int*   tlb  = (int*)(ws + TLB_OFF);
    u32*   tvl  = (u32*)(ws + TVL_OFF);
    u64*   keepw = (u64*)(ws + KEEP_OFF);
    u32*   cand_ord = (u32*)(ws + UNION_OFF);   // overlaid with mask
    u64*   mask = (u64*)(ws + UNION_OFF);       // k6 writes after k3b's last read

    hipMemsetAsync(d_ws, 0, ZERO_BYTES, stream);  // histrep, bcntrep, meta

    k1_score_hist<<<BIMG * NPROP / 4, 256, 0, stream>>>(logits, reg, props, imh, imw,
                                                        histrep, cand_ord);
    k2_scan<<<BIMG, 256, 0, stream>>>(histrep, histtot, start, startrep, meta);
    k3_compact<<<(BIMG * MCAND) / 256, 256, 0, stream>>>(cand_ord, startrep, meta, bcntrep, sel);
    k3b_fill<<<BIMG, 64, 0, stream>>>(cand_ord, meta, sel);
    k4_sortseg<<<dim3(256, BIMG), 256, 0, stream>>>(histtot, start, sel);
    k5_gather<<<BIMG, 256, 0, stream>>>(sel, reg, props, imh, imw, tbox, tsb, tsc, tlb, tvl);
    k6_mask<<<dim3(32, 32, BIMG), 64, 0, stream>>>(tsb, mask);
    k7_nms<<<BIMG, 64, 0, stream>>>(mask, tvl, keepw);
    k8_final<<<BIMG, 256, 0, stream>>>(keepw, tsc, tbox, tlb, out);
}

// Round 6
// 461.092 us; speedup vs baseline: 1.9750x; 1.0477x over previous
//
#include <hip/hip_runtime.h>
#include <stdint.h>

typedef unsigned int u32;
typedef unsigned long long u64;

#define BIMG 8
#define NPROP 4000
#define NCLS 91
#define CM1 90
#define MCAND (NPROP * CM1)      // 360000 candidates per image
#define KPRE 2048
#define NBUCKET 4096
#define NREP 8                   // counter replicas (contention /8)
#define SELCAP 16384
#define DETS 100
#define SCORE_T 0.05f
#define NMS_T 0.5f
#define BBOX_CLIP 4.135166556742356f   // log(1000/16)

// ---------------- workspace layout ----------------
// zeroed region first: histrep + bcntrep + meta
#define HISTREP_OFF ((size_t)0)                                  // u32[8][8][4096] rep-major
#define BCNTREP_OFF (HISTREP_OFF + (size_t)NREP * BIMG * NBUCKET * 4)
#define META_OFF    (BCNTREP_OFF + (size_t)NREP * BIMG * NBUCKET * 4)  // u32[8][8]
#define ZERO_BYTES  (META_OFF + 4096)
#define START_OFF   (ZERO_BYTES)                                 // u32[8][4096]
#define HISTTOT_OFF (START_OFF + (size_t)BIMG * NBUCKET * 4)     // u32[8][4096]
#define STARTREP_OFF (HISTTOT_OFF + (size_t)BIMG * NBUCKET * 4)  // u32[8][8][4096]
#define SEL_OFF     (STARTREP_OFF + (size_t)NREP * BIMG * NBUCKET * 4) // u64[8][SELCAP]
#define TBOX_OFF    (SEL_OFF + (size_t)BIMG * SELCAP * 8)        // f32[8][2048][4]
#define TSB_OFF     (TBOX_OFF + (size_t)BIMG * KPRE * 16)        // f32[8][2048][4]
#define TSC_OFF     (TSB_OFF + (size_t)BIMG * KPRE * 16)         // f32[8][2048]
#define TLB_OFF     (TSC_OFF + (size_t)BIMG * KPRE * 4)          // i32[8][2048]
#define TVL_OFF     (TLB_OFF + (size_t)BIMG * KPRE * 4)          // u32[8][2048]
#define KEEP_OFF    (TVL_OFF + (size_t)BIMG * KPRE * 4)          // u64[8][32]
// UNION: cand_ord (u32[8][360000], dead after k3b) overlays mask
// (u64[8][2048][32], first written by k6). Same stream => ordered.
#define UNION_OFF   (KEEP_OFF + (size_t)BIMG * 32 * 8)
#define UNION_BYTES ((size_t)BIMG * MCAND * 4)                   // 11.52 MB > mask's 4 MB
#define WS_NEED     (UNION_OFF + UNION_BYTES)                    // ~16.7 MB

__device__ __forceinline__ void decode_clip(const float4 rg, const float w, const float h,
                                            const float cx, const float cy,
                                            const float fw, const float fh, float bx[4]) {
    float dx = rg.x / 10.0f;
    float dy = rg.y / 10.0f;
    float dw = fminf(rg.z / 5.0f, BBOX_CLIP);
    float dh = fminf(rg.w / 5.0f, BBOX_CLIP);
    float pcx = dx * w + cx;
    float pcy = dy * h + cy;
    float pw  = expf(dw) * w;
    float phh = expf(dh) * h;
    bx[0] = fminf(fmaxf(pcx - 0.5f * pw,  0.0f), fw);
    bx[1] = fminf(fmaxf(pcy - 0.5f * phh, 0.0f), fh);
    bx[2] = fminf(fmaxf(pcx + 0.5f * pw,  0.0f), fw);
    bx[3] = fminf(fmaxf(pcy + 0.5f * phh, 0.0f), fh);
}

// K1: one wave per proposal row. Softmax(91); conservative logit-space
// prefilter (l - mx > ln(es) + ln(0.05) - 1e-3) gates the expensive
// decode+divide path; passing lanes re-test exactly (bit-identical results).
// Histogram atomics go to NREP replicas keyed by (cand_idx>>8)&7 == the
// blockIdx of k3's thread covering that candidate.
__global__ __launch_bounds__(256) void k1_score_hist(
    const float* __restrict__ logits, const float* __restrict__ reg,
    const float* __restrict__ props, const int* __restrict__ imh, const int* __restrict__ imw,
    u32* __restrict__ histrep, u32* __restrict__ cand_ord) {
    const int lane = threadIdx.x & 63;
    const int pid = blockIdx.x * 4 + (threadIdx.x >> 6);
    if (pid >= BIMG * NPROP) return;
    const int img = pid / NPROP;
    const float fw = (float)imw[0], fh = (float)imh[0];
    const float* lrow = logits + (size_t)pid * NCLS;
    float v0 = lrow[lane];
    float v1 = (lane < 27) ? lrow[lane + 64] : -3.0e38f;
    float mx = fmaxf(v0, v1);
#pragma unroll
    for (int o = 32; o > 0; o >>= 1) mx = fmaxf(mx, __shfl_xor(mx, o));
    float es = expf(v0 - mx) + ((lane < 27) ? expf(v1 - mx) : 0.0f);
#pragma unroll
    for (int o = 32; o > 0; o >>= 1) es += __shfl_xor(es, o);
    const float thr = mx + logf(es) - 2.9967323f;   // ln(0.05) - 1e-3 margin
    float4 p = reinterpret_cast<const float4*>(props)[pid];
    const float w = p.z - p.x, h = p.w - p.y;
    const float cx = p.x + 0.5f * w, cy = p.y + 0.5f * h;
    const float4* rrow = reinterpret_cast<const float4*>(reg) + (size_t)pid * NCLS;
    const int n = pid - img * NPROP;
    u32* co = cand_ord + (size_t)img * MCAND + (size_t)n * CM1;
#pragma unroll
    for (int batch = 0; batch < 2; ++batch) {
        int ci = lane + batch * 64;
        if (ci < CM1) {
            int c = ci + 1;
            float l = lrow[c];
            u32 o = 0u;
            if (l > thr) {                        // rare (~2% of lanes)
                float sc = expf(l - mx) / es;     // exact, same as before
                float4 rg = rrow[c];
                float bx[4];
                decode_clip(rg, w, h, cx, cy, fw, fh, bx);
                bool valid = (sc > SCORE_T) && (bx[2] - bx[0] >= 1.0f) && (bx[3] - bx[1] >= 1.0f);
                if (valid) {
                    o = __float_as_uint(sc) | 0x80000000u;  // sc > 0 always
                    u32 t = (u32)img * MCAND + (u32)n * CM1 + (u32)ci;
                    int rep = (int)((t >> 8) & (NREP - 1));
                    atomicAdd(&histrep[((size_t)rep * BIMG + img) * NBUCKET + (o >> 20)], 1u);
                }
            }
            co[ci] = o;
        }
    }
}

// K2: one 256-thread block per image. Sums the NREP histogram replicas,
// block-scans in descending-bucket order -> start[], per-rep sub-offsets
// startrep[], summed histtot[] (for k4), threshold bucket T, V, fillneed.
__global__ __launch_bounds__(256) void k2_scan(
    const u32* __restrict__ histrep, u32* __restrict__ histtot,
    u32* __restrict__ start, u32* __restrict__ startrep, u32* __restrict__ meta) {
    const int img = blockIdx.x;
    const int td = threadIdx.x;
    const int lane = td & 63, wv = td >> 6;
    u32 cnt[16]; u32 tsum = 0;
#pragma unroll
    for (int k = 0; k < 16; ++k) {
        const int bk = NBUCKET - 1 - (td * 16 + k);
        u32 c = 0;
#pragma unroll
        for (int r = 0; r < NREP; ++r)
            c += histrep[((size_t)r * BIMG + img) * NBUCKET + bk];
        cnt[k] = c; tsum += c;
    }
    u32 inc = tsum;
#pragma unroll
    for (int o = 1; o < 64; o <<= 1) { u32 t = __shfl_up(inc, o); if (lane >= o) inc += t; }
    __shared__ u32 wsum[4];
    __shared__ u32 TbkS, Vs;
    if (td == 0) TbkS = 0u;
    if (lane == 63) wsum[wv] = inc;
    __syncthreads();
    u32 wbase = 0;
    for (int i = 0; i < wv; ++i) wbase += wsum[i];
    if (td == 255) Vs = wbase + inc;
    u32 excl = wbase + inc - tsum;
#pragma unroll
    for (int k = 0; k < 16; ++k) {
        const int bk = NBUCKET - 1 - (td * 16 + k);
        const u32 c = cnt[k];
        start[img * NBUCKET + bk] = excl;
        histtot[img * NBUCKET + bk] = c;
        u32 sub = excl;
#pragma unroll
        for (int r = 0; r < NREP; ++r) {
            startrep[((size_t)r * BIMG + img) * NBUCKET + bk] = sub;
            sub += histrep[((size_t)r * BIMG + img) * NBUCKET + bk];
        }
        if (c > 0 && excl < KPRE && excl + c >= KPRE) TbkS = (u32)bk;  // <=1 writer
        excl += c;
    }
    __syncthreads();
    if (td == 0) {
        u32 V = Vs;
        meta[img * 8 + 0] = V;
        meta[img * 8 + 1] = TbkS;
        meta[img * 8 + 2] = (V < KPRE) ? (KPRE - V) : 0u;
    }
}

// K3: compact candidates in buckets >= T into sel[], position = per-rep
// sub-range start + per-rep atomic counter (rep = blockIdx & 7, contention /8).
// Within-bucket order is arbitrary — k4 sorts the whole segment by key.
__global__ __launch_bounds__(256) void k3_compact(
    const u32* __restrict__ cand_ord, const u32* __restrict__ startrep,
    const u32* __restrict__ meta, u32* __restrict__ bcntrep, u64* __restrict__ sel) {
    const u32 t = blockIdx.x * 256 + threadIdx.x;
    const int rep = (int)(blockIdx.x & (NREP - 1));   // == (t>>8)&7
    if (t >= (u32)(BIMG * MCAND)) return;
    const int img = t / MCAND;
    const u32 idx = t - (u32)img * MCAND;
    const u32 o = cand_ord[t];
    if (!o) return;
    const u32 bk = o >> 20;
    if (bk < meta[img * 8 + 1]) return;
    const size_t ri = ((size_t)rep * BIMG + img) * NBUCKET + bk;
    const u32 pos = startrep[ri] + atomicAdd(&bcntrep[ri], 1u);
    if (pos < SELCAP)
        sel[(size_t)img * SELCAP + pos] = ((u64)o << 32) | (u32)(~idx);
}

// K3b: rare path — fewer than KPRE valid: fill remaining slots with invalid
// candidates (score -1) in ascending-index order (lax.top_k tie semantics).
__global__ __launch_bounds__(64) void k3b_fill(
    const u32* __restrict__ cand_ord, const u32* __restrict__ meta, u64* __restrict__ sel) {
    const int img = blockIdx.x;
    const u32 need = meta[img * 8 + 2];
    if (need == 0) return;
    const u32 V = meta[img * 8 + 0];
    const int lane = threadIdx.x;
    const u32 ORDN1 = 0x407FFFFFu;  // ord_of(-1.0f)
    u32 filled = 0;
    for (u32 b0 = 0; b0 < MCAND && filled < need; b0 += 64) {
        u32 idx = b0 + lane;
        bool inv = (idx < MCAND) && (cand_ord[(size_t)img * MCAND + idx] == 0u);
        u64 bal = __ballot(inv);
        u32 pre = (u32)__popcll(bal & ((1ull << lane) - 1ull));
        if (inv && (filled + pre) < need)
            sel[(size_t)img * SELCAP + V + filled + pre] = ((u64)ORDN1 << 32) | (u32)(~idx);
        filled += (u32)__popcll(bal);
    }
}

// K4: sort each compacted bucket segment (those intersecting the top-KPRE
// region) descending by key via LDS bitonic.
__global__ __launch_bounds__(256) void k4_sortseg(
    const u32* __restrict__ histtot, const u32* __restrict__ start, u64* __restrict__ sel) {
    __shared__ u64 arr[4096];
    const int img = blockIdx.y;
    const int tid = threadIdx.x;
    for (int bk = blockIdx.x * 16; bk < blockIdx.x * 16 + 16; ++bk) {
        u32 cnt = histtot[img * NBUCKET + bk];       // uniform across block
        if (cnt < 2) continue;
        u32 st = start[img * NBUCKET + bk];
        if (st >= KPRE) continue;                    // below top region
        if (st + cnt > SELCAP) cnt = SELCAP - st;
        if (cnt > 4096) cnt = 4096;                  // pathological only
        int n = 1;
        while (n < (int)cnt) n <<= 1;
        u64* seg = sel + (size_t)img * SELCAP + st;
        for (int i = tid; i < n; i += 256) arr[i] = (i < (int)cnt) ? seg[i] : 0ull;
        __syncthreads();
        for (int k = 2; k <= n; k <<= 1)
            for (int j = k >> 1; j > 0; j >>= 1) {
                for (int i = tid; i < n; i += 256) {
                    int ixj = i ^ j;
                    if (ixj > i) {
                        u64 a = arr[i], b = arr[ixj];
                        bool swp = ((i & k) == 0) ? (a < b) : (a > b);
                        if (swp) { arr[i] = b; arr[ixj] = a; }
                    }
                }
                __syncthreads();
            }
        for (int i = tid; i < (int)cnt; i += 256) seg[i] = arr[i];
        __syncthreads();
    }
}

// K5: gather the top-2048: re-decode boxes, store score/label/valid, compute
// max coordinate and class-offset shifted boxes exactly as the reference.
__global__ __launch_bounds__(256) void k5_gather(
    const u64* __restrict__ sel, const float* __restrict__ reg, const float* __restrict__ props,
    const int* __restrict__ imh, const int* __restrict__ imw,
    float* __restrict__ tbox, float* __restrict__ tsb, float* __restrict__ tsc,
    int* __restrict__ tlb, u32* __restrict__ tvl) {
    const int img = blockIdx.x;
    const int tid = threadIdx.x;
    const float fw = (float)imw[0], fh = (float)imh[0];
    float bx[8][4];
    int lab[8];
    float lm = -3.0e38f;
#pragma unroll
    for (int t = 0; t < 8; ++t) {
        int s = t * 256 + tid;
        u64 key = sel[(size_t)img * SELCAP + s];
        u32 o = (u32)(key >> 32);
        u32 idx = ~((u32)key);
        u32 b = (o & 0x80000000u) ? (o & 0x7FFFFFFFu) : ~o;
        float sc = __uint_as_float(b);               // exact masked score roundtrip
        u32 n = idx / CM1;
        int c = (int)(idx - n * CM1) + 1;
        int pid = img * NPROP + (int)n;
        float4 p = reinterpret_cast<const float4*>(props)[pid];
        float w = p.z - p.x, h = p.w - p.y;
        float cx = p.x + 0.5f * w, cy = p.y + 0.5f * h;
        float4 rg = reinterpret_cast<const float4*>(reg)[(size_t)pid * NCLS + c];
        decode_clip(rg, w, h, cx, cy, fw, fh, bx[t]);
        lab[t] = c;
        lm = fmaxf(lm, fmaxf(fmaxf(bx[t][0], bx[t][1]), fmaxf(bx[t][2], bx[t][3])));
        reinterpret_cast<float4*>(tbox)[(size_t)img * KPRE + s] =
            make_float4(bx[t][0], bx[t][1], bx[t][2], bx[t][3]);
        tsc[(size_t)img * KPRE + s] = sc;
        tlb[(size_t)img * KPRE + s] = c;
        tvl[(size_t)img * KPRE + s] = (sc > SCORE_T) ? 1u : 0u;
    }
#pragma unroll
    for (int o2 = 32; o2 > 0; o2 >>= 1) lm = fmaxf(lm, __shfl_xor(lm, o2));
    __shared__ float wm[4];
    if ((tid & 63) == 0) wm[tid >> 6] = lm;
    __syncthreads();
    float mplus = fmaxf(fmaxf(wm[0], wm[1]), fmaxf(wm[2], wm[3])) + 1.0f;
#pragma unroll
    for (int t = 0; t < 8; ++t) {
        int s = t * 256 + tid;
        float off = (float)lab[t] * mplus;
        reinterpret_cast<float4*>(tsb)[(size_t)img * KPRE + s] =
            make_float4(bx[t][0] + off, bx[t][1] + off, bx[t][2] + off, bx[t][3] + off);
    }
}

// K6: suppression bitmask. Block = 64 rows x 64 cols; bit set iff
// iou(shifted_i, shifted_j) > thresh and j > i (reference formula verbatim).
__global__ __launch_bounds__(64) void k6_mask(
    const float* __restrict__ tsb, u64* __restrict__ mask) {
    const int img = blockIdx.z;
    const int j0 = blockIdx.x * 64;
    const int i0 = blockIdx.y * 64;
    const int tid = threadIdx.x;
    __shared__ float4 cb[64];
    __shared__ float ca[64];
    float4 c = reinterpret_cast<const float4*>(tsb)[(size_t)img * KPRE + j0 + tid];
    cb[tid] = c;
    ca[tid] = (c.z - c.x) * (c.w - c.y);
    __syncthreads();
    const int i = i0 + tid;
    float4 r = reinterpret_cast<const float4*>(tsb)[(size_t)img * KPRE + i];
    float ra = (r.z - r.x) * (r.w - r.y);
    u64 bits = 0ull;
#pragma unroll 8
    for (int jj = 0; jj < 64; ++jj) {
        int j = j0 + jj;
        float4 cc = cb[jj];
        float wv = fmaxf(fminf(r.z, cc.z) - fmaxf(r.x, cc.x), 0.0f);
        float hv = fmaxf(fminf(r.w, cc.w) - fmaxf(r.y, cc.y), 0.0f);
        float inter = wv * hv;
        float iou = inter / ((ra + ca[jj]) - inter);   // NaN compares false, like jnp
        if ((iou > NMS_T) && (j > i)) bits |= (1ull << jj);
    }
    mask[((size_t)img * KPRE + i) * 32 + (j0 >> 6)] = bits;
}

// ---- K7 v5: greedy scan; serial chain in SALU, row data staged via LDS ----
// r4 evidence (VGPR=52): compiler sinks named register prefetches to their
// uses -> 32 serialized L2 round-trips/block (102 us). Fix: DMA the whole
// 64-row block (16 KB contiguous) into LDS with global_load_lds width=16
// (async, no VGPR destination, can't be "sunk" onto the chain), overlap it
// with the serial recurrence on prefetched diag registers, then apply from
// LDS with cheap ds_read_b64.
__device__ __forceinline__ u64 rdlane64(u64 v, int l) {
    u32 lo = (u32)__builtin_amdgcn_readlane((int)(u32)v, l);
    u32 hi = (u32)__builtin_amdgcn_readlane((int)(u32)(v >> 32), l);
    return ((u64)hi << 32) | lo;
}

__device__ __forceinline__ void g2l16(const void* g, void* l) {
    __builtin_amdgcn_global_load_lds(
        (const __attribute__((address_space(1))) void*)g,
        (__attribute__((address_space(3))) void*)l, 16, 0, 0);
}

__global__ __launch_bounds__(64) void k7_nms(
    const u64* __restrict__ mask, const u32* __restrict__ tvl, u64* __restrict__ keepw) {
    __shared__ u64 lbuf[2048];           // 16 KB: one 64-row block (64 x 32 u64)
    const int img = blockIdx.x;
    const int lane = threadIdx.x;
    const int half = lane >> 5;          // 0: rows 2g, 1: rows 2g+1
    const u64* mrow = mask + (size_t)img * KPRE * 32;

    // removed: lane l<32 holds partial word l (half A); lanes 32-63 partial
    // word l-32 (half B). Invalid rows pre-removed into half A.
    u64 removed = 0ull;
    for (int w = 0; w < 32; ++w) {
        bool tv = tvl[(size_t)img * KPRE + w * 64 + lane] != 0u;
        u64 bal = __ballot(tv);
        if (lane == w) removed = ~bal;
    }

    // diag for block 0: lane u holds word 0 of row u
    u64 diag = mrow[(size_t)lane * 32];
    u64 rp = rdlane64(removed, 0) | rdlane64(removed, 32);

#pragma unroll 1
    for (int b = 0; b < 32; ++b) {
        const size_t base32 = (size_t)b * 2048;   // u64 index of row 64b, word 0

        // ---- issue async DMA of this block's 16 KB into LDS ----
        {
            const char* gsrc = (const char*)(mrow + base32) + (size_t)lane * 16;
            char* ldst = (char*)lbuf;
#pragma unroll
            for (int t = 0; t < 16; ++t)
                g2l16(gsrc + (size_t)t * 1024, ldst + (size_t)t * 1024);
        }

        // prefetch next block's diag word into registers (off-chain VMEM)
        u64 diagn = 0ull;
        if (b + 1 < 32)
            diagn = mrow[base32 + 2048 + (size_t)lane * 32 + (b + 1)];

        // ---- serial in-block recurrence (pure scalar chain), overlaps DMA ----
        u64 A = rp;
#pragma unroll
        for (int u = 0; u < 64; ++u) {
            u64 row = rdlane64(diag, u);
            if (!((A >> u) & 1ull)) A |= row;      // row has only bits > u in-block
        }
        const u64 keptw = ~A;

        // ---- wait DMA, apply kept rows from LDS ----
        asm volatile("s_waitcnt vmcnt(0)" ::: "memory");
#pragma unroll
        for (int g = 0; g < 32; ++g) {
            u64 v = lbuf[64 * g + lane];           // lane<32: row 2g word lane;
                                                   // lane>=32: row 2g+1 word lane-32
            removed |= (((keptw >> (2 * g + half)) & 1ull) ? v : 0ull);
        }

        // seed word for next block (after application)
        const int nb = (b + 1) & 31;
        rp = rdlane64(removed, nb) | rdlane64(removed, 32 + nb);
        diag = diagn;
    }

    // merge the two halves and emit keep words
    removed |= __shfl_xor(removed, 32);
    if (lane < 32) keepw[img * 32 + lane] = ~removed;
}

// K8: final top-100 per image (bitonic over 2048 keys) + output writes.
__global__ __launch_bounds__(256) void k8_final(
    const u64* __restrict__ keepw, const float* __restrict__ tsc,
    const float* __restrict__ tbox, const int* __restrict__ tlb,
    float* __restrict__ out) {
    __shared__ u64 arr[KPRE];
    const int img = blockIdx.x;
    const int tid = threadIdx.x;
#pragma unroll
    for (int t = 0; t < 8; ++t) {
        int s = t * 256 + tid;
        u64 kw = keepw[img * 32 + (s >> 6)];
        bool kept = (kw >> (s & 63)) & 1ull;
        float ks = kept ? tsc[(size_t)img * KPRE + s] : -1.0f;
        u32 b = __float_as_uint(ks);
        u32 o = (b & 0x80000000u) ? ~b : (b | 0x80000000u);
        arr[s] = ((u64)o << 32) | (u32)(~(u32)s);
    }
    __syncthreads();
    for (int k = 2; k <= KPRE; k <<= 1)
        for (int j = k >> 1; j > 0; j >>= 1) {
            for (int i = tid; i < KPRE; i += 256) {
                int ixj = i ^ j;
                if (ixj > i) {
                    u64 a = arr[i], bb = arr[ixj];
                    bool swp = ((i & k) == 0) ? (a < bb) : (a > bb);
                    if (swp) { arr[i] = bb; arr[ixj] = a; }
                }
            }
            __syncthreads();
        }
    if (tid < DETS) {
        u64 key = arr[tid];
        u32 o = (u32)(key >> 32);
        u32 b = (o & 0x80000000u) ? (o & 0x7FFFFFFFu) : ~o;
        float fs = __uint_as_float(b);
        u32 s = ~((u32)key);
        bool fv = fs > SCORE_T;
        float4 bxv = make_float4(0.0f, 0.0f, 0.0f, 0.0f);
        float lb = -1.0f, scw = 0.0f;
        if (fv) {
            bxv = reinterpret_cast<const float4*>(tbox)[(size_t)img * KPRE + s];
            lb = (float)tlb[(size_t)img * KPRE + s];
            scw = fs;
        }
        float* ob = out + (size_t)img * DETS * 4 + (size_t)tid * 4;
        ob[0] = bxv.x; ob[1] = bxv.y; ob[2] = bxv.z; ob[3] = bxv.w;
        out[BIMG * DETS * 4 + img * DETS + tid] = scw;   // scores at 3200
        out[BIMG * DETS * 5 + img * DETS + tid] = lb;    // labels at 4000
    }
}

extern "C" void kernel_launch(void* const* d_in, const int* in_sizes, int n_in,
                              void* d_out, int out_size, void* d_ws, size_t ws_size,
                              hipStream_t stream) {
    const float* logits = (const float*)d_in[0];
    const float* reg    = (const float*)d_in[1];
    const float* props  = (const float*)d_in[2];
    const int*   imh    = (const int*)d_in[3];
    const int*   imw    = (const int*)d_in[4];
    float* out = (float*)d_out;
    char* ws = (char*)d_ws;
    if (ws_size < WS_NEED) return;  // ~16.7 MB needed

    u32* histrep  = (u32*)(ws + HISTREP_OFF);
    u32* bcntrep  = (u32*)(ws + BCNTREP_OFF);
    u32* meta     = (u32*)(ws + META_OFF);
    u32* start    = (u32*)(ws + START_OFF);
    u32* histtot  = (u32*)(ws + HISTTOT_OFF);
    u32* startrep = (u32*)(ws + STARTREP_OFF);
    u64* sel  = (u64*)(ws + SEL_OFF);
    float* tbox = (float*)(ws + TBOX_OFF);
    float* tsb  = (float*)(ws + TSB_OFF);
    float* tsc  = (float*)(ws + TSC_OFF);
    int*   tlb  = (int*)(ws + TLB_OFF);
    u32*   tvl  = (u32*)(ws + TVL_OFF);
    u64*   keepw = (u64*)(ws + KEEP_OFF);
    u32*   cand_ord = (u32*)(ws + UNION_OFF);   // overlaid with mask
    u64*   mask = (u64*)(ws + UNION_OFF);       // k6 writes after k3b's last read

    hipMemsetAsync(d_ws, 0, ZERO_BYTES, stream);  // histrep, bcntrep, meta

    k1_score_hist<<<BIMG * NPROP / 4, 256, 0, stream>>>(logits, reg, props, imh, imw,
                                                        histrep, cand_ord);
    k2_scan<<<BIMG, 256, 0, stream>>>(histrep, histtot, start, startrep, meta);
    k3_compact<<<(BIMG * MCAND) / 256, 256, 0, stream>>>(cand_ord, startrep, meta, bcntrep, sel);
    k3b_fill<<<BIMG, 64, 0, stream>>>(cand_ord, meta, sel);
    k4_sortseg<<<dim3(256, BIMG), 256, 0, stream>>>(histtot, start, sel);
    k5_gather<<<BIMG, 256, 0, stream>>>(sel, reg, props, imh, imw, tbox, tsb, tsc, tlb, tvl);
    k6_mask<<<dim3(32, 32, BIMG), 64, 0, stream>>>(tsb, mask);
    k7_nms<<<BIMG, 64, 0, stream>>>(mask, tvl, keepw);
    k8_final<<<BIMG, 256, 0, stream>>>(keepw, tsc, tbox, tlb, out);
}

// Round 7
// 397.587 us; speedup vs baseline: 2.2905x; 1.1597x over previous
//
#include <hip/hip_runtime.h>
#include <stdint.h>

typedef unsigned int u32;
typedef unsigned long long u64;

#define BIMG 8
#define NPROP 4000
#define NCLS 91
#define CM1 90
#define MCAND (NPROP * CM1)      // 360000 candidates per image
#define KPRE 2048
#define NBUCKET 4096
#define NREP 8                   // counter replicas (contention /8)
#define SELCAP 16384
#define DETS 100
#define WLCAP 2048               // worklist capacity per image (max real ~1025)
#define SCORE_T 0.05f
#define NMS_T 0.5f
#define BBOX_CLIP 4.135166556742356f   // log(1000/16)

// ---------------- workspace layout ----------------
// zeroed region first: histrep + bcntrep + meta
#define HISTREP_OFF ((size_t)0)                                  // u32[8][8][4096] rep-major
#define BCNTREP_OFF (HISTREP_OFF + (size_t)NREP * BIMG * NBUCKET * 4)
#define META_OFF    (BCNTREP_OFF + (size_t)NREP * BIMG * NBUCKET * 4)  // u32[8][8]
#define ZERO_BYTES  (META_OFF + 4096)
#define START_OFF   (ZERO_BYTES)                                 // u32[8][4096]
#define HISTTOT_OFF (START_OFF + (size_t)BIMG * NBUCKET * 4)     // u32[8][4096]
#define STARTREP_OFF (HISTTOT_OFF + (size_t)BIMG * NBUCKET * 4)  // u32[8][8][4096]
#define SEL_OFF     (STARTREP_OFF + (size_t)NREP * BIMG * NBUCKET * 4) // u64[8][SELCAP]
#define TBOX_OFF    (SEL_OFF + (size_t)BIMG * SELCAP * 8)        // f32[8][2048][4]
#define TSB_OFF     (TBOX_OFF + (size_t)BIMG * KPRE * 16)        // f32[8][2048][4]
#define TSC_OFF     (TSB_OFF + (size_t)BIMG * KPRE * 16)         // f32[8][2048]
#define TLB_OFF     (TSC_OFF + (size_t)BIMG * KPRE * 4)          // i32[8][2048]
#define TVL_OFF     (TLB_OFF + (size_t)BIMG * KPRE * 4)          // u32[8][2048]
#define KEEP_OFF    (TVL_OFF + (size_t)BIMG * KPRE * 4)          // u64[8][32]
#define WLIST_OFF   (KEEP_OFF + (size_t)BIMG * 32 * 8)           // u32[8][WLCAP]
// UNION: cand_ord (u32[8][360000], dead after k3b) overlays mask
// (u64[8][2048][32], first written by k6). Same stream => ordered.
#define UNION_OFF   (WLIST_OFF + (size_t)BIMG * WLCAP * 4)
#define UNION_BYTES ((size_t)BIMG * MCAND * 4)                   // 11.52 MB > mask's 4 MB
#define WS_NEED     (UNION_OFF + UNION_BYTES)                    // ~16.8 MB

__device__ __forceinline__ void decode_clip(const float4 rg, const float w, const float h,
                                            const float cx, const float cy,
                                            const float fw, const float fh, float bx[4]) {
    float dx = rg.x / 10.0f;
    float dy = rg.y / 10.0f;
    float dw = fminf(rg.z / 5.0f, BBOX_CLIP);
    float dh = fminf(rg.w / 5.0f, BBOX_CLIP);
    float pcx = dx * w + cx;
    float pcy = dy * h + cy;
    float pw  = expf(dw) * w;
    float phh = expf(dh) * h;
    bx[0] = fminf(fmaxf(pcx - 0.5f * pw,  0.0f), fw);
    bx[1] = fminf(fmaxf(pcy - 0.5f * phh, 0.0f), fh);
    bx[2] = fminf(fmaxf(pcx + 0.5f * pw,  0.0f), fw);
    bx[3] = fminf(fmaxf(pcy + 0.5f * phh, 0.0f), fh);
}

// K1: one wave per proposal row. Softmax(91); conservative logit-space
// prefilter gates the expensive decode+divide path; passing lanes re-test
// exactly (bit-identical). Histogram atomics to NREP replicas (contention /8).
__global__ __launch_bounds__(256) void k1_score_hist(
    const float* __restrict__ logits, const float* __restrict__ reg,
    const float* __restrict__ props, const int* __restrict__ imh, const int* __restrict__ imw,
    u32* __restrict__ histrep, u32* __restrict__ cand_ord) {
    const int lane = threadIdx.x & 63;
    const int pid = blockIdx.x * 4 + (threadIdx.x >> 6);
    if (pid >= BIMG * NPROP) return;
    const int img = pid / NPROP;
    const float fw = (float)imw[0], fh = (float)imh[0];
    const float* lrow = logits + (size_t)pid * NCLS;
    float v0 = lrow[lane];
    float v1 = (lane < 27) ? lrow[lane + 64] : -3.0e38f;
    float mx = fmaxf(v0, v1);
#pragma unroll
    for (int o = 32; o > 0; o >>= 1) mx = fmaxf(mx, __shfl_xor(mx, o));
    float es = expf(v0 - mx) + ((lane < 27) ? expf(v1 - mx) : 0.0f);
#pragma unroll
    for (int o = 32; o > 0; o >>= 1) es += __shfl_xor(es, o);
    const float thr = mx + logf(es) - 2.9967323f;   // ln(0.05) - 1e-3 margin
    float4 p = reinterpret_cast<const float4*>(props)[pid];
    const float w = p.z - p.x, h = p.w - p.y;
    const float cx = p.x + 0.5f * w, cy = p.y + 0.5f * h;
    const float4* rrow = reinterpret_cast<const float4*>(reg) + (size_t)pid * NCLS;
    const int n = pid - img * NPROP;
    u32* co = cand_ord + (size_t)img * MCAND + (size_t)n * CM1;
#pragma unroll
    for (int batch = 0; batch < 2; ++batch) {
        int ci = lane + batch * 64;
        if (ci < CM1) {
            int c = ci + 1;
            float l = lrow[c];
            u32 o = 0u;
            if (l > thr) {                        // rare (~2% of lanes)
                float sc = expf(l - mx) / es;     // exact, same as before
                float4 rg = rrow[c];
                float bx[4];
                decode_clip(rg, w, h, cx, cy, fw, fh, bx);
                bool valid = (sc > SCORE_T) && (bx[2] - bx[0] >= 1.0f) && (bx[3] - bx[1] >= 1.0f);
                if (valid) {
                    o = __float_as_uint(sc) | 0x80000000u;  // sc > 0 always
                    u32 t = (u32)img * MCAND + (u32)n * CM1 + (u32)ci;
                    int rep = (int)((t >> 8) & (NREP - 1));
                    atomicAdd(&histrep[((size_t)rep * BIMG + img) * NBUCKET + (o >> 20)], 1u);
                }
            }
            co[ci] = o;
        }
    }
}

// K2: one 256-thread block per image. Sums the NREP histogram replicas,
// block-scans in descending-bucket order -> start[], per-rep sub-offsets
// startrep[], histtot[], threshold bucket T, V, fillneed, AND a worklist of
// buckets needing a sort (cnt>=2 && start<KPRE; provably <=1025 entries) so
// k4 can load-balance across blocks instead of serializing clustered buckets.
__global__ __launch_bounds__(256) void k2_scan(
    const u32* __restrict__ histrep, u32* __restrict__ histtot,
    u32* __restrict__ start, u32* __restrict__ startrep, u32* __restrict__ meta,
    u32* __restrict__ wlist) {
    const int img = blockIdx.x;
    const int td = threadIdx.x;
    const int lane = td & 63, wv = td >> 6;
    u32 cnt[16]; u32 tsum = 0;
#pragma unroll
    for (int k = 0; k < 16; ++k) {
        const int bk = NBUCKET - 1 - (td * 16 + k);
        u32 c = 0;
#pragma unroll
        for (int r = 0; r < NREP; ++r)
            c += histrep[((size_t)r * BIMG + img) * NBUCKET + bk];
        cnt[k] = c; tsum += c;
    }
    u32 inc = tsum;
#pragma unroll
    for (int o = 1; o < 64; o <<= 1) { u32 t = __shfl_up(inc, o); if (lane >= o) inc += t; }
    __shared__ u32 wsum[4];
    __shared__ u32 TbkS, Vs;
    if (td == 0) TbkS = 0u;
    if (lane == 63) wsum[wv] = inc;
    __syncthreads();
    u32 wbase = 0;
    for (int i = 0; i < wv; ++i) wbase += wsum[i];
    if (td == 255) Vs = wbase + inc;
    const u32 excl0 = wbase + inc - tsum;
    u32 excl = excl0;
#pragma unroll
    for (int k = 0; k < 16; ++k) {
        const int bk = NBUCKET - 1 - (td * 16 + k);
        const u32 c = cnt[k];
        start[img * NBUCKET + bk] = excl;
        histtot[img * NBUCKET + bk] = c;
        u32 sub = excl;
#pragma unroll
        for (int r = 0; r < NREP; ++r) {
            startrep[((size_t)r * BIMG + img) * NBUCKET + bk] = sub;
            sub += histrep[((size_t)r * BIMG + img) * NBUCKET + bk];
        }
        if (c > 0 && excl < KPRE && excl + c >= KPRE) TbkS = (u32)bk;  // <=1 writer
        excl += c;
    }
    // ---- worklist emission: buckets with cnt>=2 && start<KPRE ----
    u32 qcnt = 0;
    {
        u32 e = excl0;
#pragma unroll
        for (int k = 0; k < 16; ++k) {
            if (cnt[k] >= 2 && e < KPRE) ++qcnt;
            e += cnt[k];
        }
    }
    u32 qinc = qcnt;
#pragma unroll
    for (int o = 1; o < 64; o <<= 1) { u32 t = __shfl_up(qinc, o); if (lane >= o) qinc += t; }
    __shared__ u32 qws[4];
    if (lane == 63) qws[wv] = qinc;
    __syncthreads();
    u32 qbase = 0;
    for (int i = 0; i < wv; ++i) qbase += qws[i];
    u32 qoff = qbase + qinc - qcnt;
    {
        u32 e = excl0;
#pragma unroll
        for (int k = 0; k < 16; ++k) {
            const int bk = NBUCKET - 1 - (td * 16 + k);
            if (cnt[k] >= 2 && e < KPRE && qoff < WLCAP) wlist[img * WLCAP + (qoff++)] = (u32)bk;
            e += cnt[k];
        }
    }
    if (td == 255) meta[img * 8 + 3] = qbase + qinc;   // worklist count
    __syncthreads();
    if (td == 0) {
        u32 V = Vs;
        meta[img * 8 + 0] = V;
        meta[img * 8 + 1] = TbkS;
        meta[img * 8 + 2] = (V < KPRE) ? (KPRE - V) : 0u;
    }
}

// K3: compact candidates in buckets >= T into sel[], position = per-rep
// sub-range start + per-rep atomic counter (rep = blockIdx & 7).
__global__ __launch_bounds__(256) void k3_compact(
    const u32* __restrict__ cand_ord, const u32* __restrict__ startrep,
    const u32* __restrict__ meta, u32* __restrict__ bcntrep, u64* __restrict__ sel) {
    const u32 t = blockIdx.x * 256 + threadIdx.x;
    const int rep = (int)(blockIdx.x & (NREP - 1));   // == (t>>8)&7
    if (t >= (u32)(BIMG * MCAND)) return;
    const int img = t / MCAND;
    const u32 idx = t - (u32)img * MCAND;
    const u32 o = cand_ord[t];
    if (!o) return;
    const u32 bk = o >> 20;
    if (bk < meta[img * 8 + 1]) return;
    const size_t ri = ((size_t)rep * BIMG + img) * NBUCKET + bk;
    const u32 pos = startrep[ri] + atomicAdd(&bcntrep[ri], 1u);
    if (pos < SELCAP)
        sel[(size_t)img * SELCAP + pos] = ((u64)o << 32) | (u32)(~idx);
}

// K3b: rare path — fewer than KPRE valid: fill remaining slots with invalid
// candidates (score -1) in ascending-index order (lax.top_k tie semantics).
__global__ __launch_bounds__(64) void k3b_fill(
    const u32* __restrict__ cand_ord, const u32* __restrict__ meta, u64* __restrict__ sel) {
    const int img = blockIdx.x;
    const u32 need = meta[img * 8 + 2];
    if (need == 0) return;
    const u32 V = meta[img * 8 + 0];
    const int lane = threadIdx.x;
    const u32 ORDN1 = 0x407FFFFFu;  // ord_of(-1.0f)
    u32 filled = 0;
    for (u32 b0 = 0; b0 < MCAND && filled < need; b0 += 64) {
        u32 idx = b0 + lane;
        bool inv = (idx < MCAND) && (cand_ord[(size_t)img * MCAND + idx] == 0u);
        u64 bal = __ballot(inv);
        u32 pre = (u32)__popcll(bal & ((1ull << lane) - 1ull));
        if (inv && (filled + pre) < need)
            sel[(size_t)img * SELCAP + V + filled + pre] = ((u64)ORDN1 << 32) | (u32)(~idx);
        filled += (u32)__popcll(bal);
    }
}

// K4 v2: worklist-driven. Grid (64, BIMG); block x sorts worklist entries
// x, x+64, ... (one LDS bitonic per bucket segment). Removes the r6 tail
// where 2-3 blocks serially sorted all clustered buckets of an image.
__global__ __launch_bounds__(256) void k4_sortseg(
    const u32* __restrict__ histtot, const u32* __restrict__ start,
    const u32* __restrict__ meta, const u32* __restrict__ wlist, u64* __restrict__ sel) {
    __shared__ u64 arr[4096];
    const int img = blockIdx.y;
    const int tid = threadIdx.x;
    const u32 wcount = meta[img * 8 + 3];
    for (u32 wi = blockIdx.x; wi < wcount; wi += gridDim.x) {
        const u32 bk = (wi < WLCAP) ? wlist[img * WLCAP + wi] : 0u;
        u32 cnt = histtot[img * NBUCKET + bk];       // uniform across block
        u32 st = start[img * NBUCKET + bk];
        if (cnt < 2 || st >= KPRE) continue;         // defensive; wlist guarantees
        if (st + cnt > SELCAP) cnt = SELCAP - st;
        if (cnt > 4096) cnt = 4096;                  // pathological only
        int n = 1;
        while (n < (int)cnt) n <<= 1;
        u64* seg = sel + (size_t)img * SELCAP + st;
        for (int i = tid; i < n; i += 256) arr[i] = (i < (int)cnt) ? seg[i] : 0ull;
        __syncthreads();
        for (int k = 2; k <= n; k <<= 1)
            for (int j = k >> 1; j > 0; j >>= 1) {
                for (int i = tid; i < n; i += 256) {
                    int ixj = i ^ j;
                    if (ixj > i) {
                        u64 a = arr[i], b = arr[ixj];
                        bool swp = ((i & k) == 0) ? (a < b) : (a > b);
                        if (swp) { arr[i] = b; arr[ixj] = a; }
                    }
                }
                __syncthreads();
            }
        for (int i = tid; i < (int)cnt; i += 256) seg[i] = arr[i];
        __syncthreads();
    }
}

// K5: gather the top-2048: re-decode boxes, store score/label/valid, compute
// max coordinate and class-offset shifted boxes exactly as the reference.
__global__ __launch_bounds__(256) void k5_gather(
    const u64* __restrict__ sel, const float* __restrict__ reg, const float* __restrict__ props,
    const int* __restrict__ imh, const int* __restrict__ imw,
    float* __restrict__ tbox, float* __restrict__ tsb, float* __restrict__ tsc,
    int* __restrict__ tlb, u32* __restrict__ tvl) {
    const int img = blockIdx.x;
    const int tid = threadIdx.x;
    const float fw = (float)imw[0], fh = (float)imh[0];
    float bx[8][4];
    int lab[8];
    float lm = -3.0e38f;
#pragma unroll
    for (int t = 0; t < 8; ++t) {
        int s = t * 256 + tid;
        u64 key = sel[(size_t)img * SELCAP + s];
        u32 o = (u32)(key >> 32);
        u32 idx = ~((u32)key);
        u32 b = (o & 0x80000000u) ? (o & 0x7FFFFFFFu) : ~o;
        float sc = __uint_as_float(b);               // exact masked score roundtrip
        u32 n = idx / CM1;
        int c = (int)(idx - n * CM1) + 1;
        int pid = img * NPROP + (int)n;
        float4 p = reinterpret_cast<const float4*>(props)[pid];
        float w = p.z - p.x, h = p.w - p.y;
        float cx = p.x + 0.5f * w, cy = p.y + 0.5f * h;
        float4 rg = reinterpret_cast<const float4*>(reg)[(size_t)pid * NCLS + c];
        decode_clip(rg, w, h, cx, cy, fw, fh, bx[t]);
        lab[t] = c;
        lm = fmaxf(lm, fmaxf(fmaxf(bx[t][0], bx[t][1]), fmaxf(bx[t][2], bx[t][3])));
        reinterpret_cast<float4*>(tbox)[(size_t)img * KPRE + s] =
            make_float4(bx[t][0], bx[t][1], bx[t][2], bx[t][3]);
        tsc[(size_t)img * KPRE + s] = sc;
        tlb[(size_t)img * KPRE + s] = c;
        tvl[(size_t)img * KPRE + s] = (sc > SCORE_T) ? 1u : 0u;
    }
#pragma unroll
    for (int o2 = 32; o2 > 0; o2 >>= 1) lm = fmaxf(lm, __shfl_xor(lm, o2));
    __shared__ float wm[4];
    if ((tid & 63) == 0) wm[tid >> 6] = lm;
    __syncthreads();
    float mplus = fmaxf(fmaxf(wm[0], wm[1]), fmaxf(wm[2], wm[3])) + 1.0f;
#pragma unroll
    for (int t = 0; t < 8; ++t) {
        int s = t * 256 + tid;
        float off = (float)lab[t] * mplus;
        reinterpret_cast<float4*>(tsb)[(size_t)img * KPRE + s] =
            make_float4(bx[t][0] + off, bx[t][1] + off, bx[t][2] + off, bx[t][3] + off);
    }
}

// K6: suppression bitmask. Block = 64 rows x 64 cols; bit set iff
// iou(shifted_i, shifted_j) > thresh and j > i (reference formula verbatim).
__global__ __launch_bounds__(64) void k6_mask(
    const float* __restrict__ tsb, u64* __restrict__ mask) {
    const int img = blockIdx.z;
    const int j0 = blockIdx.x * 64;
    const int i0 = blockIdx.y * 64;
    const int tid = threadIdx.x;
    __shared__ float4 cb[64];
    __shared__ float ca[64];
    float4 c = reinterpret_cast<const float4*>(tsb)[(size_t)img * KPRE + j0 + tid];
    cb[tid] = c;
    ca[tid] = (c.z - c.x) * (c.w - c.y);
    __syncthreads();
    const int i = i0 + tid;
    float4 r = reinterpret_cast<const float4*>(tsb)[(size_t)img * KPRE + i];
    float ra = (r.z - r.x) * (r.w - r.y);
    u64 bits = 0ull;
#pragma unroll 8
    for (int jj = 0; jj < 64; ++jj) {
        int j = j0 + jj;
        float4 cc = cb[jj];
        float wv = fmaxf(fminf(r.z, cc.z) - fmaxf(r.x, cc.x), 0.0f);
        float hv = fmaxf(fminf(r.w, cc.w) - fmaxf(r.y, cc.y), 0.0f);
        float inter = wv * hv;
        float iou = inter / ((ra + ca[jj]) - inter);   // NaN compares false, like jnp
        if ((iou > NMS_T) && (j > i)) bits |= (1ull << jj);
    }
    mask[((size_t)img * KPRE + i) * 32 + (j0 >> 6)] = bits;
}

// K7: greedy scan; serial chain in SALU, row data staged via LDS DMA
// (global_load_lds width=16), apply via ds_read_b64. See r6 notes.
__device__ __forceinline__ u64 rdlane64(u64 v, int l) {
    u32 lo = (u32)__builtin_amdgcn_readlane((int)(u32)v, l);
    u32 hi = (u32)__builtin_amdgcn_readlane((int)(u32)(v >> 32), l);
    return ((u64)hi << 32) | lo;
}

__device__ __forceinline__ void g2l16(const void* g, void* l) {
    __builtin_amdgcn_global_load_lds(
        (const __attribute__((address_space(1))) void*)g,
        (__attribute__((address_space(3))) void*)l, 16, 0, 0);
}

__global__ __launch_bounds__(64) void k7_nms(
    const u64* __restrict__ mask, const u32* __restrict__ tvl, u64* __restrict__ keepw) {
    __shared__ u64 lbuf[2048];           // 16 KB: one 64-row block (64 x 32 u64)
    const int img = blockIdx.x;
    const int lane = threadIdx.x;
    const int half = lane >> 5;          // 0: rows 2g, 1: rows 2g+1
    const u64* mrow = mask + (size_t)img * KPRE * 32;

    u64 removed = 0ull;
    for (int w = 0; w < 32; ++w) {
        bool tv = tvl[(size_t)img * KPRE + w * 64 + lane] != 0u;
        u64 bal = __ballot(tv);
        if (lane == w) removed = ~bal;
    }

    u64 diag = mrow[(size_t)lane * 32];
    u64 rp = rdlane64(removed, 0) | rdlane64(removed, 32);

#pragma unroll 1
    for (int b = 0; b < 32; ++b) {
        const size_t base32 = (size_t)b * 2048;   // u64 index of row 64b, word 0

        {
            const char* gsrc = (const char*)(mrow + base32) + (size_t)lane * 16;
            char* ldst = (char*)lbuf;
#pragma unroll
            for (int t = 0; t < 16; ++t)
                g2l16(gsrc + (size_t)t * 1024, ldst + (size_t)t * 1024);
        }

        u64 diagn = 0ull;
        if (b + 1 < 32)
            diagn = mrow[base32 + 2048 + (size_t)lane * 32 + (b + 1)];

        u64 A = rp;
#pragma unroll
        for (int u = 0; u < 64; ++u) {
            u64 row = rdlane64(diag, u);
            if (!((A >> u) & 1ull)) A |= row;      // row has only bits > u in-block
        }
        const u64 keptw = ~A;

        asm volatile("s_waitcnt vmcnt(0)" ::: "memory");
#pragma unroll
        for (int g = 0; g < 32; ++g) {
            u64 v = lbuf[64 * g + lane];
            removed |= (((keptw >> (2 * g + half)) & 1ull) ? v : 0ull);
        }

        const int nb = (b + 1) & 31;
        rp = rdlane64(removed, nb) | rdlane64(removed, 32 + nb);
        diag = diagn;
    }

    removed |= __shfl_xor(removed, 32);
    if (lane < 32) keepw[img * 32 + lane] = ~removed;
}

// K8: final top-100 per image (bitonic over 2048 keys) + output writes.
__global__ __launch_bounds__(256) void k8_final(
    const u64* __restrict__ keepw, const float* __restrict__ tsc,
    const float* __restrict__ tbox, const int* __restrict__ tlb,
    float* __restrict__ out) {
    __shared__ u64 arr[KPRE];
    const int img = blockIdx.x;
    const int tid = threadIdx.x;
#pragma unroll
    for (int t = 0; t < 8; ++t) {
        int s = t * 256 + tid;
        u64 kw = keepw[img * 32 + (s >> 6)];
        bool kept = (kw >> (s & 63)) & 1ull;
        float ks = kept ? tsc[(size_t)img * KPRE + s] : -1.0f;
        u32 b = __float_as_uint(ks);
        u32 o = (b & 0x80000000u) ? ~b : (b | 0x80000000u);
        arr[s] = ((u64)o << 32) | (u32)(~(u32)s);
    }
    __syncthreads();
    for (int k = 2; k <= KPRE; k <<= 1)
        for (int j = k >> 1; j > 0; j >>= 1) {
            for (int i = tid; i < KPRE; i += 256) {
                int ixj = i ^ j;
                if (ixj > i) {
                    u64 a = arr[i], bb = arr[ixj];
                    bool swp = ((i & k) == 0) ? (a < bb) : (a > bb);
                    if (swp) { arr[i] = bb; arr[ixj] = a; }
                }
            }
            __syncthreads();
        }
    if (tid < DETS) {
        u64 key = arr[tid];
        u32 o = (u32)(key >> 32);
        u32 b = (o & 0x80000000u) ? (o & 0x7FFFFFFFu) : ~o;
        float fs = __uint_as_float(b);
        u32 s = ~((u32)key);
        bool fv = fs > SCORE_T;
        float4 bxv = make_float4(0.0f, 0.0f, 0.0f, 0.0f);
        float lb = -1.0f, scw = 0.0f;
        if (fv) {
            bxv = reinterpret_cast<const float4*>(tbox)[(size_t)img * KPRE + s];
            lb = (float)tlb[(size_t)img * KPRE + s];
            scw = fs;
        }
        float* ob = out + (size_t)img * DETS * 4 + (size_t)tid * 4;
        ob[0] = bxv.x; ob[1] = bxv.y; ob[2] = bxv.z; ob[3] = bxv.w;
        out[BIMG * DETS * 4 + img * DETS + tid] = scw;   // scores at 3200
        out[BIMG * DETS * 5 + img * DETS + tid] = lb;    // labels at 4000
    }
}

extern "C" void kernel_launch(void* const* d_in, const int* in_sizes, int n_in,
                              void* d_out, int out_size, void* d_ws, size_t ws_size,
                              hipStream_t stream) {
    const float* logits = (const float*)d_in[0];
    const float* reg    = (const float*)d_in[1];
    const float* props  = (const float*)d_in[2];
    const int*   imh    = (const int*)d_in[3];
    const int*   imw    = (const int*)d_in[4];
    float* out = (float*)d_out;
    char* ws = (char*)d_ws;
    if (ws_size < WS_NEED) return;  // ~16.8 MB needed

    u32* histrep  = (u32*)(ws + HISTREP_OFF);
    u32* bcntrep  = (u32*)(ws + BCNTREP_OFF);
    u32* meta     = (u32*)(ws + META_OFF);
    u32* start    = (u32*)(ws + START_OFF);
    u32* histtot  = (u32*)(ws + HISTTOT_OFF);
    u32* startrep = (u32*)(ws + STARTREP_OFF);
    u64* sel  = (u64*)(ws + SEL_OFF);
    float* tbox = (float*)(ws + TBOX_OFF);
    float* tsb  = (float*)(ws + TSB_OFF);
    float* tsc  = (float*)(ws + TSC_OFF);
    int*   tlb  = (int*)(ws + TLB_OFF);
    u32*   tvl  = (u32*)(ws + TVL_OFF);
    u64*   keepw = (u64*)(ws + KEEP_OFF);
    u32*   wlist = (u32*)(ws + WLIST_OFF);
    u32*   cand_ord = (u32*)(ws + UNION_OFF);   // overlaid with mask
    u64*   mask = (u64*)(ws + UNION_OFF);       // k6 writes after k3b's last read

    hipMemsetAsync(d_ws, 0, ZERO_BYTES, stream);  // histrep, bcntrep, meta

    k1_score_hist<<<BIMG * NPROP / 4, 256, 0, stream>>>(logits, reg, props, imh, imw,
                                                        histrep, cand_ord);
    k2_scan<<<BIMG, 256, 0, stream>>>(histrep, histtot, start, startrep, meta, wlist);
    k3_compact<<<(BIMG * MCAND) / 256, 256, 0, stream>>>(cand_ord, startrep, meta, bcntrep, sel);
    k3b_fill<<<BIMG, 64, 0, stream>>>(cand_ord, meta, sel);
    k4_sortseg<<<dim3(64, BIMG), 256, 0, stream>>>(histtot, start, meta, wlist, sel);
    k5_gather<<<BIMG, 256, 0, stream>>>(sel, reg, props, imh, imw, tbox, tsb, tsc, tlb, tvl);
    k6_mask<<<dim3(32, 32, BIMG), 64, 0, stream>>>(tsb, mask);
    k7_nms<<<BIMG, 64, 0, stream>>>(mask, tvl, keepw);
    k8_final<<<BIMG, 256, 0, stream>>>(keepw, tsc, tbox, tlb, out);
}

// Round 8
// 393.617 us; speedup vs baseline: 2.3136x; 1.0101x over previous
//
#include <hip/hip_runtime.h>
#include <stdint.h>

typedef unsigned int u32;
typedef unsigned long long u64;
typedef __attribute__((ext_vector_type(2))) unsigned long long u64x2;

#define BIMG 8
#define NPROP 4000
#define NCLS 91
#define CM1 90
#define MCAND (NPROP * CM1)      // 360000 candidates per image
#define KPRE 2048
#define NBUCKET 4096
#define NREP 8                   // counter replicas (contention /8)
#define SELCAP 16384
#define DETS 100
#define WLCAP 2048               // worklist capacity per image (max real ~1025)
#define SCORE_T 0.05f
#define NMS_T 0.5f
#define BBOX_CLIP 4.135166556742356f   // log(1000/16)

// ---------------- workspace layout ----------------
// zeroed region first: histrep + bcntrep + meta
#define HISTREP_OFF ((size_t)0)                                  // u32[8][8][4096] rep-major
#define BCNTREP_OFF (HISTREP_OFF + (size_t)NREP * BIMG * NBUCKET * 4)
#define META_OFF    (BCNTREP_OFF + (size_t)NREP * BIMG * NBUCKET * 4)  // u32[8][8]
#define ZERO_BYTES  (META_OFF + 4096)
#define START_OFF   (ZERO_BYTES)                                 // u32[8][4096]
#define HISTTOT_OFF (START_OFF + (size_t)BIMG * NBUCKET * 4)     // u32[8][4096]
#define STARTREP_OFF (HISTTOT_OFF + (size_t)BIMG * NBUCKET * 4)  // u32[8][8][4096]
#define SEL_OFF     (STARTREP_OFF + (size_t)NREP * BIMG * NBUCKET * 4) // u64[8][SELCAP]
#define TBOX_OFF    (SEL_OFF + (size_t)BIMG * SELCAP * 8)        // f32[8][2048][4]
#define TSB_OFF     (TBOX_OFF + (size_t)BIMG * KPRE * 16)        // f32[8][2048][4]
#define TSC_OFF     (TSB_OFF + (size_t)BIMG * KPRE * 16)         // f32[8][2048]
#define TLB_OFF     (TSC_OFF + (size_t)BIMG * KPRE * 4)          // i32[8][2048]
#define TVL_OFF     (TLB_OFF + (size_t)BIMG * KPRE * 4)          // u32[8][2048]
#define KEEP_OFF    (TVL_OFF + (size_t)BIMG * KPRE * 4)          // u64[8][32]
#define WLIST_OFF   (KEEP_OFF + (size_t)BIMG * 32 * 8)           // u32[8][WLCAP]
// UNION: cand_ord (u32[8][360000], dead after k3b) overlays mask
// (u64[8][2048][32], first written by k6). Same stream => ordered.
#define UNION_OFF   (WLIST_OFF + (size_t)BIMG * WLCAP * 4)
#define UNION_BYTES ((size_t)BIMG * MCAND * 4)                   // 11.52 MB > mask's 4 MB
#define WS_NEED     (UNION_OFF + UNION_BYTES)                    // ~16.8 MB

__device__ __forceinline__ void decode_clip(const float4 rg, const float w, const float h,
                                            const float cx, const float cy,
                                            const float fw, const float fh, float bx[4]) {
    float dx = rg.x / 10.0f;
    float dy = rg.y / 10.0f;
    float dw = fminf(rg.z / 5.0f, BBOX_CLIP);
    float dh = fminf(rg.w / 5.0f, BBOX_CLIP);
    float pcx = dx * w + cx;
    float pcy = dy * h + cy;
    float pw  = expf(dw) * w;
    float phh = expf(dh) * h;
    bx[0] = fminf(fmaxf(pcx - 0.5f * pw,  0.0f), fw);
    bx[1] = fminf(fmaxf(pcy - 0.5f * phh, 0.0f), fh);
    bx[2] = fminf(fmaxf(pcx + 0.5f * pw,  0.0f), fw);
    bx[3] = fminf(fmaxf(pcy + 0.5f * phh, 0.0f), fh);
}

// K1: one wave per proposal row. Softmax(91); conservative logit-space
// prefilter gates the expensive decode+divide path; passing lanes re-test
// exactly (bit-identical). Histogram atomics to NREP replicas (contention /8).
__global__ __launch_bounds__(256) void k1_score_hist(
    const float* __restrict__ logits, const float* __restrict__ reg,
    const float* __restrict__ props, const int* __restrict__ imh, const int* __restrict__ imw,
    u32* __restrict__ histrep, u32* __restrict__ cand_ord) {
    const int lane = threadIdx.x & 63;
    const int pid = blockIdx.x * 4 + (threadIdx.x >> 6);
    if (pid >= BIMG * NPROP) return;
    const int img = pid / NPROP;
    const float fw = (float)imw[0], fh = (float)imh[0];
    const float* lrow = logits + (size_t)pid * NCLS;
    float v0 = lrow[lane];
    float v1 = (lane < 27) ? lrow[lane + 64] : -3.0e38f;
    float mx = fmaxf(v0, v1);
#pragma unroll
    for (int o = 32; o > 0; o >>= 1) mx = fmaxf(mx, __shfl_xor(mx, o));
    float es = expf(v0 - mx) + ((lane < 27) ? expf(v1 - mx) : 0.0f);
#pragma unroll
    for (int o = 32; o > 0; o >>= 1) es += __shfl_xor(es, o);
    const float thr = mx + logf(es) - 2.9967323f;   // ln(0.05) - 1e-3 margin
    float4 p = reinterpret_cast<const float4*>(props)[pid];
    const float w = p.z - p.x, h = p.w - p.y;
    const float cx = p.x + 0.5f * w, cy = p.y + 0.5f * h;
    const float4* rrow = reinterpret_cast<const float4*>(reg) + (size_t)pid * NCLS;
    const int n = pid - img * NPROP;
    u32* co = cand_ord + (size_t)img * MCAND + (size_t)n * CM1;
#pragma unroll
    for (int batch = 0; batch < 2; ++batch) {
        int ci = lane + batch * 64;
        if (ci < CM1) {
            int c = ci + 1;
            float l = lrow[c];
            u32 o = 0u;
            if (l > thr) {                        // rare (~2% of lanes)
                float sc = expf(l - mx) / es;     // exact, same as before
                float4 rg = rrow[c];
                float bx[4];
                decode_clip(rg, w, h, cx, cy, fw, fh, bx);
                bool valid = (sc > SCORE_T) && (bx[2] - bx[0] >= 1.0f) && (bx[3] - bx[1] >= 1.0f);
                if (valid) {
                    o = __float_as_uint(sc) | 0x80000000u;  // sc > 0 always
                    u32 t = (u32)img * MCAND + (u32)n * CM1 + (u32)ci;
                    int rep = (int)((t >> 8) & (NREP - 1));
                    atomicAdd(&histrep[((size_t)rep * BIMG + img) * NBUCKET + (o >> 20)], 1u);
                }
            }
            co[ci] = o;
        }
    }
}

// K2: one 256-thread block per image. Sums the NREP histogram replicas,
// block-scans in descending-bucket order -> start[], per-rep sub-offsets
// startrep[], histtot[], threshold bucket T, V, fillneed, AND a worklist of
// buckets needing a sort (cnt>=2 && start<KPRE) for k4 load balancing.
__global__ __launch_bounds__(256) void k2_scan(
    const u32* __restrict__ histrep, u32* __restrict__ histtot,
    u32* __restrict__ start, u32* __restrict__ startrep, u32* __restrict__ meta,
    u32* __restrict__ wlist) {
    const int img = blockIdx.x;
    const int td = threadIdx.x;
    const int lane = td & 63, wv = td >> 6;
    u32 cnt[16]; u32 tsum = 0;
#pragma unroll
    for (int k = 0; k < 16; ++k) {
        const int bk = NBUCKET - 1 - (td * 16 + k);
        u32 c = 0;
#pragma unroll
        for (int r = 0; r < NREP; ++r)
            c += histrep[((size_t)r * BIMG + img) * NBUCKET + bk];
        cnt[k] = c; tsum += c;
    }
    u32 inc = tsum;
#pragma unroll
    for (int o = 1; o < 64; o <<= 1) { u32 t = __shfl_up(inc, o); if (lane >= o) inc += t; }
    __shared__ u32 wsum[4];
    __shared__ u32 TbkS, Vs;
    if (td == 0) TbkS = 0u;
    if (lane == 63) wsum[wv] = inc;
    __syncthreads();
    u32 wbase = 0;
    for (int i = 0; i < wv; ++i) wbase += wsum[i];
    if (td == 255) Vs = wbase + inc;
    const u32 excl0 = wbase + inc - tsum;
    u32 excl = excl0;
#pragma unroll
    for (int k = 0; k < 16; ++k) {
        const int bk = NBUCKET - 1 - (td * 16 + k);
        const u32 c = cnt[k];
        start[img * NBUCKET + bk] = excl;
        histtot[img * NBUCKET + bk] = c;
        u32 sub = excl;
#pragma unroll
        for (int r = 0; r < NREP; ++r) {
            startrep[((size_t)r * BIMG + img) * NBUCKET + bk] = sub;
            sub += histrep[((size_t)r * BIMG + img) * NBUCKET + bk];
        }
        if (c > 0 && excl < KPRE && excl + c >= KPRE) TbkS = (u32)bk;  // <=1 writer
        excl += c;
    }
    // ---- worklist emission: buckets with cnt>=2 && start<KPRE ----
    u32 qcnt = 0;
    {
        u32 e = excl0;
#pragma unroll
        for (int k = 0; k < 16; ++k) {
            if (cnt[k] >= 2 && e < KPRE) ++qcnt;
            e += cnt[k];
        }
    }
    u32 qinc = qcnt;
#pragma unroll
    for (int o = 1; o < 64; o <<= 1) { u32 t = __shfl_up(qinc, o); if (lane >= o) qinc += t; }
    __shared__ u32 qws[4];
    if (lane == 63) qws[wv] = qinc;
    __syncthreads();
    u32 qbase = 0;
    for (int i = 0; i < wv; ++i) qbase += qws[i];
    u32 qoff = qbase + qinc - qcnt;
    {
        u32 e = excl0;
#pragma unroll
        for (int k = 0; k < 16; ++k) {
            const int bk = NBUCKET - 1 - (td * 16 + k);
            if (cnt[k] >= 2 && e < KPRE && qoff < WLCAP) wlist[img * WLCAP + (qoff++)] = (u32)bk;
            e += cnt[k];
        }
    }
    if (td == 255) meta[img * 8 + 3] = qbase + qinc;   // worklist count
    __syncthreads();
    if (td == 0) {
        u32 V = Vs;
        meta[img * 8 + 0] = V;
        meta[img * 8 + 1] = TbkS;
        meta[img * 8 + 2] = (V < KPRE) ? (KPRE - V) : 0u;
    }
}

// K3: compact candidates in buckets >= T into sel[], position = per-rep
// sub-range start + per-rep atomic counter (rep = blockIdx & 7).
__global__ __launch_bounds__(256) void k3_compact(
    const u32* __restrict__ cand_ord, const u32* __restrict__ startrep,
    const u32* __restrict__ meta, u32* __restrict__ bcntrep, u64* __restrict__ sel) {
    const u32 t = blockIdx.x * 256 + threadIdx.x;
    const int rep = (int)(blockIdx.x & (NREP - 1));   // == (t>>8)&7
    if (t >= (u32)(BIMG * MCAND)) return;
    const int img = t / MCAND;
    const u32 idx = t - (u32)img * MCAND;
    const u32 o = cand_ord[t];
    if (!o) return;
    const u32 bk = o >> 20;
    if (bk < meta[img * 8 + 1]) return;
    const size_t ri = ((size_t)rep * BIMG + img) * NBUCKET + bk;
    const u32 pos = startrep[ri] + atomicAdd(&bcntrep[ri], 1u);
    if (pos < SELCAP)
        sel[(size_t)img * SELCAP + pos] = ((u64)o << 32) | (u32)(~idx);
}

// K3b: rare path — fewer than KPRE valid: fill remaining slots with invalid
// candidates (score -1) in ascending-index order (lax.top_k tie semantics).
__global__ __launch_bounds__(64) void k3b_fill(
    const u32* __restrict__ cand_ord, const u32* __restrict__ meta, u64* __restrict__ sel) {
    const int img = blockIdx.x;
    const u32 need = meta[img * 8 + 2];
    if (need == 0) return;
    const u32 V = meta[img * 8 + 0];
    const int lane = threadIdx.x;
    const u32 ORDN1 = 0x407FFFFFu;  // ord_of(-1.0f)
    u32 filled = 0;
    for (u32 b0 = 0; b0 < MCAND && filled < need; b0 += 64) {
        u32 idx = b0 + lane;
        bool inv = (idx < MCAND) && (cand_ord[(size_t)img * MCAND + idx] == 0u);
        u64 bal = __ballot(inv);
        u32 pre = (u32)__popcll(bal & ((1ull << lane) - 1ull));
        if (inv && (filled + pre) < need)
            sel[(size_t)img * SELCAP + V + filled + pre] = ((u64)ORDN1 << 32) | (u32)(~idx);
        filled += (u32)__popcll(bal);
    }
}

// K4: worklist-driven. Grid (64, BIMG); block x sorts worklist entries
// x, x+64, ... (one LDS bitonic per bucket segment).
__global__ __launch_bounds__(256) void k4_sortseg(
    const u32* __restrict__ histtot, const u32* __restrict__ start,
    const u32* __restrict__ meta, const u32* __restrict__ wlist, u64* __restrict__ sel) {
    __shared__ u64 arr[4096];
    const int img = blockIdx.y;
    const int tid = threadIdx.x;
    const u32 wcount = meta[img * 8 + 3];
    for (u32 wi = blockIdx.x; wi < wcount; wi += gridDim.x) {
        const u32 bk = (wi < WLCAP) ? wlist[img * WLCAP + wi] : 0u;
        u32 cnt = histtot[img * NBUCKET + bk];       // uniform across block
        u32 st = start[img * NBUCKET + bk];
        if (cnt < 2 || st >= KPRE) continue;         // defensive; wlist guarantees
        if (st + cnt > SELCAP) cnt = SELCAP - st;
        if (cnt > 4096) cnt = 4096;                  // pathological only
        int n = 1;
        while (n < (int)cnt) n <<= 1;
        u64* seg = sel + (size_t)img * SELCAP + st;
        for (int i = tid; i < n; i += 256) arr[i] = (i < (int)cnt) ? seg[i] : 0ull;
        __syncthreads();
        for (int k = 2; k <= n; k <<= 1)
            for (int j = k >> 1; j > 0; j >>= 1) {
                for (int i = tid; i < n; i += 256) {
                    int ixj = i ^ j;
                    if (ixj > i) {
                        u64 a = arr[i], b = arr[ixj];
                        bool swp = ((i & k) == 0) ? (a < b) : (a > b);
                        if (swp) { arr[i] = b; arr[ixj] = a; }
                    }
                }
                __syncthreads();
            }
        for (int i = tid; i < (int)cnt; i += 256) seg[i] = arr[i];
        __syncthreads();
    }
}

// K5: gather the top-2048: re-decode boxes, store score/label/valid, compute
// max coordinate and class-offset shifted boxes exactly as the reference.
__global__ __launch_bounds__(256) void k5_gather(
    const u64* __restrict__ sel, const float* __restrict__ reg, const float* __restrict__ props,
    const int* __restrict__ imh, const int* __restrict__ imw,
    float* __restrict__ tbox, float* __restrict__ tsb, float* __restrict__ tsc,
    int* __restrict__ tlb, u32* __restrict__ tvl) {
    const int img = blockIdx.x;
    const int tid = threadIdx.x;
    const float fw = (float)imw[0], fh = (float)imh[0];
    float bx[8][4];
    int lab[8];
    float lm = -3.0e38f;
#pragma unroll
    for (int t = 0; t < 8; ++t) {
        int s = t * 256 + tid;
        u64 key = sel[(size_t)img * SELCAP + s];
        u32 o = (u32)(key >> 32);
        u32 idx = ~((u32)key);
        u32 b = (o & 0x80000000u) ? (o & 0x7FFFFFFFu) : ~o;
        float sc = __uint_as_float(b);               // exact masked score roundtrip
        u32 n = idx / CM1;
        int c = (int)(idx - n * CM1) + 1;
        int pid = img * NPROP + (int)n;
        float4 p = reinterpret_cast<const float4*>(props)[pid];
        float w = p.z - p.x, h = p.w - p.y;
        float cx = p.x + 0.5f * w, cy = p.y + 0.5f * h;
        float4 rg = reinterpret_cast<const float4*>(reg)[(size_t)pid * NCLS + c];
        decode_clip(rg, w, h, cx, cy, fw, fh, bx[t]);
        lab[t] = c;
        lm = fmaxf(lm, fmaxf(fmaxf(bx[t][0], bx[t][1]), fmaxf(bx[t][2], bx[t][3])));
        reinterpret_cast<float4*>(tbox)[(size_t)img * KPRE + s] =
            make_float4(bx[t][0], bx[t][1], bx[t][2], bx[t][3]);
        tsc[(size_t)img * KPRE + s] = sc;
        tlb[(size_t)img * KPRE + s] = c;
        tvl[(size_t)img * KPRE + s] = (sc > SCORE_T) ? 1u : 0u;
    }
#pragma unroll
    for (int o2 = 32; o2 > 0; o2 >>= 1) lm = fmaxf(lm, __shfl_xor(lm, o2));
    __shared__ float wm[4];
    if ((tid & 63) == 0) wm[tid >> 6] = lm;
    __syncthreads();
    float mplus = fmaxf(fmaxf(wm[0], wm[1]), fmaxf(wm[2], wm[3])) + 1.0f;
#pragma unroll
    for (int t = 0; t < 8; ++t) {
        int s = t * 256 + tid;
        float off = (float)lab[t] * mplus;
        reinterpret_cast<float4*>(tsb)[(size_t)img * KPRE + s] =
            make_float4(bx[t][0] + off, bx[t][1] + off, bx[t][2] + off, bx[t][3] + off);
    }
}

// K6: suppression bitmask. Block = 64 rows x 64 cols; bit set iff
// iou(shifted_i, shifted_j) > thresh and j > i (reference formula verbatim).
__global__ __launch_bounds__(64) void k6_mask(
    const float* __restrict__ tsb, u64* __restrict__ mask) {
    const int img = blockIdx.z;
    const int j0 = blockIdx.x * 64;
    const int i0 = blockIdx.y * 64;
    const int tid = threadIdx.x;
    __shared__ float4 cb[64];
    __shared__ float ca[64];
    float4 c = reinterpret_cast<const float4*>(tsb)[(size_t)img * KPRE + j0 + tid];
    cb[tid] = c;
    ca[tid] = (c.z - c.x) * (c.w - c.y);
    __syncthreads();
    const int i = i0 + tid;
    float4 r = reinterpret_cast<const float4*>(tsb)[(size_t)img * KPRE + i];
    float ra = (r.z - r.x) * (r.w - r.y);
    u64 bits = 0ull;
#pragma unroll 8
    for (int jj = 0; jj < 64; ++jj) {
        int j = j0 + jj;
        float4 cc = cb[jj];
        float wv = fmaxf(fminf(r.z, cc.z) - fmaxf(r.x, cc.x), 0.0f);
        float hv = fmaxf(fminf(r.w, cc.w) - fmaxf(r.y, cc.y), 0.0f);
        float inter = wv * hv;
        float iou = inter / ((ra + ca[jj]) - inter);   // NaN compares false, like jnp
        if ((iou > NMS_T) && (j > i)) bits |= (1ull << jj);
    }
    mask[((size_t)img * KPRE + i) * 32 + (j0 >> 6)] = bits;
}

// ---- K7 v6: SALU serial chain + double-buffered LDS DMA + b128 apply ----
// r7 evidence (VGPR=68, 87us): single-buffer DMA wait + 32 ds_read_b64/lane
// serialized by register pressure (~6.5k cy/stage). Fixes:
//  (a) double-buffer: DMA for stage b+1 issued at stage b top; apply waits
//      with counted vmcnt(17) (in-order retirement => current DMA done,
//      17 = next stage's 16 DMA + 1 diag prefetch still outstanding).
//  (b) apply via 16 ds_read_b128/lane: lane l accumulates words
//      (2(l&15), +1) over rows 4k+(l>>4) into ONE register pair (4-way
//      partials per word; seed = 4x readlane; final merge = 2x shfl_xor).
__device__ __forceinline__ u64 rdlane64(u64 v, int l) {
    u32 lo = (u32)__builtin_amdgcn_readlane((int)(u32)v, l);
    u32 hi = (u32)__builtin_amdgcn_readlane((int)(u32)(v >> 32), l);
    return ((u64)hi << 32) | lo;
}

__device__ __forceinline__ void g2l16(const void* g, void* l) {
    __builtin_amdgcn_global_load_lds(
        (const __attribute__((address_space(1))) void*)g,
        (__attribute__((address_space(3))) void*)l, 16, 0, 0);
}

__global__ __launch_bounds__(64) void k7_nms(
    const u64* __restrict__ mask, const u32* __restrict__ tvl, u64* __restrict__ keepw) {
    __shared__ u64 lbuf[2][2048];        // 2 x 16 KB double buffer
    const int img = blockIdx.x;
    const int lane = threadIdx.x;
    const int lg = lane >> 4;            // row-offset selector 0..3
    const u64* mrow = mask + (size_t)img * KPRE * 32;

    // init: ballot per word (uniform); acc pair covers words 2(l&15), +1.
    // All 4 lanes of a pair carry the same init (OR-idempotent).
    u64 accx = 0ull, accy = 0ull, rp = 0ull;
    for (int w = 0; w < 32; ++w) {
        bool tv = tvl[(size_t)img * KPRE + w * 64 + lane] != 0u;
        u64 iw = ~__ballot(tv);          // uniform across wave
        if (w == 0) rp = iw;
        if ((lane & 15) == (w >> 1)) { if (w & 1) accy = iw; else accx = iw; }
    }

    // pre-loop: DMA stage 0 into buf0; diag for stage 0
    {
        const char* gsrc = (const char*)mrow + (size_t)lane * 16;
#pragma unroll
        for (int t = 0; t < 16; ++t)
            g2l16(gsrc + (size_t)t * 1024, (char*)&lbuf[0][0] + (size_t)t * 1024);
    }
    u64 diag = mrow[(size_t)lane * 32];  // word 0 of row 'lane'

#pragma unroll 1
    for (int b = 0; b < 32; ++b) {
        const size_t base32 = (size_t)b * 2048;
        const u64* cbuf = &lbuf[b & 1][0];

        // ---- issue next stage's diag prefetch FIRST, then its DMA ----
        u64 diagn = 0ull;
        if (b + 1 < 32) {
            diagn = mrow[base32 + 2048 + (size_t)lane * 32 + (b + 1)];
            const char* gsrc = (const char*)(mrow + base32 + 2048) + (size_t)lane * 16;
            char* nb_l = (char*)&lbuf[(b + 1) & 1][0];
#pragma unroll
            for (int t = 0; t < 16; ++t)
                g2l16(gsrc + (size_t)t * 1024, nb_l + (size_t)t * 1024);
        }

        // ---- serial in-block recurrence (scalar chain) ----
        u64 A = rp;
#pragma unroll
        for (int u = 0; u < 64; ++u) {
            u64 row = rdlane64(diag, u);
            if (!((A >> u) & 1ull)) A |= row;      // row has only bits > u in-block
        }
        const u64 keptw = ~A;

        // ---- wait for CURRENT buffer's DMA (counted; next stage's 17 ops
        //      remain in flight), then apply from LDS ----
        if (b + 1 < 32) asm volatile("s_waitcnt vmcnt(17)" ::: "memory");
        else            asm volatile("s_waitcnt vmcnt(0)" ::: "memory");

#define LDV(K) u64x2 v##K = *(const u64x2*)&cbuf[128 * (K) + 2 * lane];
#define PRV(K) { u32 nib = (u32)(keptw >> (4 * (K))) & 15u; \
                 u32 kb = (nib >> lg) & 1u; \
                 accx |= kb ? v##K.x : 0ull; accy |= kb ? v##K.y : 0ull; }
        LDV(0) LDV(1) LDV(2) LDV(3)
        LDV(4) LDV(5) LDV(6) LDV(7)     PRV(0) PRV(1) PRV(2) PRV(3)
        LDV(8) LDV(9) LDV(10) LDV(11)   PRV(4) PRV(5) PRV(6) PRV(7)
        LDV(12) LDV(13) LDV(14) LDV(15) PRV(8) PRV(9) PRV(10) PRV(11)
        PRV(12) PRV(13) PRV(14) PRV(15)
#undef LDV
#undef PRV

        // ---- seed word b+1 from the 4 partials holding that word ----
        const int nb2 = b + 1;
        if (nb2 < 32) {
            u64 asel = (nb2 & 1) ? accy : accx;
            const int sl = (nb2 >> 1) & 15;
            rp = rdlane64(asel, sl) | rdlane64(asel, sl + 16) |
                 rdlane64(asel, sl + 32) | rdlane64(asel, sl + 48);
        }
        diag = diagn;
    }

    // merge 4-way partials and emit keep words
    accx |= __shfl_xor(accx, 16); accx |= __shfl_xor(accx, 32);
    accy |= __shfl_xor(accy, 16); accy |= __shfl_xor(accy, 32);
    if (lane < 16) {
        keepw[img * 32 + 2 * lane]     = ~accx;
        keepw[img * 32 + 2 * lane + 1] = ~accy;
    }
}

// K8: final top-100 per image (bitonic over 2048 keys) + output writes.
__global__ __launch_bounds__(256) void k8_final(
    const u64* __restrict__ keepw, const float* __restrict__ tsc,
    const float* __restrict__ tbox, const int* __restrict__ tlb,
    float* __restrict__ out) {
    __shared__ u64 arr[KPRE];
    const int img = blockIdx.x;
    const int tid = threadIdx.x;
#pragma unroll
    for (int t = 0; t < 8; ++t) {
        int s = t * 256 + tid;
        u64 kw = keepw[img * 32 + (s >> 6)];
        bool kept = (kw >> (s & 63)) & 1ull;
        float ks = kept ? tsc[(size_t)img * KPRE + s] : -1.0f;
        u32 b = __float_as_uint(ks);
        u32 o = (b & 0x80000000u) ? ~b : (b | 0x80000000u);
        arr[s] = ((u64)o << 32) | (u32)(~(u32)s);
    }
    __syncthreads();
    for (int k = 2; k <= KPRE; k <<= 1)
        for (int j = k >> 1; j > 0; j >>= 1) {
            for (int i = tid; i < KPRE; i += 256) {
                int ixj = i ^ j;
                if (ixj > i) {
                    u64 a = arr[i], bb = arr[ixj];
                    bool swp = ((i & k) == 0) ? (a < bb) : (a > bb);
                    if (swp) { arr[i] = bb; arr[ixj] = a; }
                }
            }
            __syncthreads();
        }
    if (tid < DETS) {
        u64 key = arr[tid];
        u32 o = (u32)(key >> 32);
        u32 b = (o & 0x80000000u) ? (o & 0x7FFFFFFFu) : ~o;
        float fs = __uint_as_float(b);
        u32 s = ~((u32)key);
        bool fv = fs > SCORE_T;
        float4 bxv = make_float4(0.0f, 0.0f, 0.0f, 0.0f);
        float lb = -1.0f, scw = 0.0f;
        if (fv) {
            bxv = reinterpret_cast<const float4*>(tbox)[(size_t)img * KPRE + s];
            lb = (float)tlb[(size_t)img * KPRE + s];
            scw = fs;
        }
        float* ob = out + (size_t)img * DETS * 4 + (size_t)tid * 4;
        ob[0] = bxv.x; ob[1] = bxv.y; ob[2] = bxv.z; ob[3] = bxv.w;
        out[BIMG * DETS * 4 + img * DETS + tid] = scw;   // scores at 3200
        out[BIMG * DETS * 5 + img * DETS + tid] = lb;    // labels at 4000
    }
}

extern "C" void kernel_launch(void* const* d_in, const int* in_sizes, int n_in,
                              void* d_out, int out_size, void* d_ws, size_t ws_size,
                              hipStream_t stream) {
    const float* logits = (const float*)d_in[0];
    const float* reg    = (const float*)d_in[1];
    const float* props  = (const float*)d_in[2];
    const int*   imh    = (const int*)d_in[3];
    const int*   imw    = (const int*)d_in[4];
    float* out = (float*)d_out;
    char* ws = (char*)d_ws;
    if (ws_size < WS_NEED) return;  // ~16.8 MB needed

    u32* histrep  = (u32*)(ws + HISTREP_OFF);
    u32* bcntrep  = (u32*)(ws + BCNTREP_OFF);
    u32* meta     = (u32*)(ws + META_OFF);
    u32* start    = (u32*)(ws + START_OFF);
    u32* histtot  = (u32*)(ws + HISTTOT_OFF);
    u32* startrep = (u32*)(ws + STARTREP_OFF);
    u64* sel  = (u64*)(ws + SEL_OFF);
    float* tbox = (float*)(ws + TBOX_OFF);
    float* tsb  = (float*)(ws + TSB_OFF);
    float* tsc  = (float*)(ws + TSC_OFF);
    int*   tlb  = (int*)(ws + TLB_OFF);
    u32*   tvl  = (u32*)(ws + TVL_OFF);
    u64*   keepw = (u64*)(ws + KEEP_OFF);
    u32*   wlist = (u32*)(ws + WLIST_OFF);
    u32*   cand_ord = (u32*)(ws + UNION_OFF);   // overlaid with mask
    u64*   mask = (u64*)(ws + UNION_OFF);       // k6 writes after k3b's last read

    hipMemsetAsync(d_ws, 0, ZERO_BYTES, stream);  // histrep, bcntrep, meta

    k1_score_hist<<<BIMG * NPROP / 4, 256, 0, stream>>>(logits, reg, props, imh, imw,
                                                        histrep, cand_ord);
    k2_scan<<<BIMG, 256, 0, stream>>>(histrep, histtot, start, startrep, meta, wlist);
    k3_compact<<<(BIMG * MCAND) / 256, 256, 0, stream>>>(cand_ord, startrep, meta, bcntrep, sel);
    k3b_fill<<<BIMG, 64, 0, stream>>>(cand_ord, meta, sel);
    k4_sortseg<<<dim3(64, BIMG), 256, 0, stream>>>(histtot, start, meta, wlist, sel);
    k5_gather<<<BIMG, 256, 0, stream>>>(sel, reg, props, imh, imw, tbox, tsb, tsc, tlb, tvl);
    k6_mask<<<dim3(32, 32, BIMG), 64, 0, stream>>>(tsb, mask);
    k7_nms<<<BIMG, 64, 0, stream>>>(mask, tvl, keepw);
    k8_final<<<BIMG, 256, 0, stream>>>(keepw, tsc, tbox, tlb, out);
}

// Round 9
// 272.776 us; speedup vs baseline: 3.3386x; 1.4430x over previous
//
#include <hip/hip_runtime.h>
#include <stdint.h>

typedef unsigned int u32;
typedef unsigned long long u64;
typedef __attribute__((ext_vector_type(2))) unsigned long long u64x2;

#define BIMG 8
#define NPROP 4000
#define NCLS 91
#define CM1 90
#define MCAND (NPROP * CM1)      // 360000 candidates per image
#define KPRE 2048
#define NBUCKET 4096
#define NREP 8                   // counter replicas (contention /8)
#define SELCAP 16384
#define DETS 100
#define WLCAP 2048               // worklist capacity per image (max real ~1025)
#define SCORE_T 0.05f
#define NMS_T 0.5f
#define BBOX_CLIP 4.135166556742356f   // log(1000/16)

// ---------------- workspace layout ----------------
// zeroed region first: histrep + bcntrep + meta
#define HISTREP_OFF ((size_t)0)                                  // u32[8][8][4096] rep-major
#define BCNTREP_OFF (HISTREP_OFF + (size_t)NREP * BIMG * NBUCKET * 4)
#define META_OFF    (BCNTREP_OFF + (size_t)NREP * BIMG * NBUCKET * 4)  // u32[8][8]
#define ZERO_BYTES  (META_OFF + 4096)
#define START_OFF   (ZERO_BYTES)                                 // u32[8][4096]
#define HISTTOT_OFF (START_OFF + (size_t)BIMG * NBUCKET * 4)     // u32[8][4096]
#define STARTREP_OFF (HISTTOT_OFF + (size_t)BIMG * NBUCKET * 4)  // u32[8][8][4096]
#define SEL_OFF     (STARTREP_OFF + (size_t)NREP * BIMG * NBUCKET * 4) // u64[8][SELCAP]
#define TBOX_OFF    (SEL_OFF + (size_t)BIMG * SELCAP * 8)        // f32[8][2048][4]
#define TSB_OFF     (TBOX_OFF + (size_t)BIMG * KPRE * 16)        // f32[8][2048][4]
#define TSC_OFF     (TSB_OFF + (size_t)BIMG * KPRE * 16)         // f32[8][2048]
#define TLB_OFF     (TSC_OFF + (size_t)BIMG * KPRE * 4)          // i32[8][2048]
#define TVL_OFF     (TLB_OFF + (size_t)BIMG * KPRE * 4)          // u32[8][2048]
#define KEEP_OFF    (TVL_OFF + (size_t)BIMG * KPRE * 4)          // u64[8][32]
#define WLIST_OFF   (KEEP_OFF + (size_t)BIMG * 32 * 8)           // u32[8][WLCAP]
// UNION: cand_ord (u32[8][360000], dead after k3b) overlays mask
// (u64[8][2048][32], memset to 0 after k3b, filled by k6). Same stream => ordered.
#define UNION_OFF   (WLIST_OFF + (size_t)BIMG * WLCAP * 4)
#define UNION_BYTES ((size_t)BIMG * MCAND * 4)                   // 11.52 MB > mask's 4 MB
#define MASK_BYTES  ((size_t)BIMG * KPRE * 32 * 8)               // 4 MB
#define WS_NEED     (UNION_OFF + UNION_BYTES)                    // ~16.8 MB

__device__ __forceinline__ void decode_clip(const float4 rg, const float w, const float h,
                                            const float cx, const float cy,
                                            const float fw, const float fh, float bx[4]) {
    float dx = rg.x / 10.0f;
    float dy = rg.y / 10.0f;
    float dw = fminf(rg.z / 5.0f, BBOX_CLIP);
    float dh = fminf(rg.w / 5.0f, BBOX_CLIP);
    float pcx = dx * w + cx;
    float pcy = dy * h + cy;
    float pw  = expf(dw) * w;
    float phh = expf(dh) * h;
    bx[0] = fminf(fmaxf(pcx - 0.5f * pw,  0.0f), fw);
    bx[1] = fminf(fmaxf(pcy - 0.5f * phh, 0.0f), fh);
    bx[2] = fminf(fmaxf(pcx + 0.5f * pw,  0.0f), fw);
    bx[3] = fminf(fmaxf(pcy + 0.5f * phh, 0.0f), fh);
}

// K1: one wave per proposal row. Softmax(91); conservative logit-space
// prefilter gates the expensive decode+divide path; passing lanes re-test
// exactly (bit-identical). Histogram atomics to NREP replicas (contention /8).
__global__ __launch_bounds__(256) void k1_score_hist(
    const float* __restrict__ logits, const float* __restrict__ reg,
    const float* __restrict__ props, const int* __restrict__ imh, const int* __restrict__ imw,
    u32* __restrict__ histrep, u32* __restrict__ cand_ord) {
    const int lane = threadIdx.x & 63;
    const int pid = blockIdx.x * 4 + (threadIdx.x >> 6);
    if (pid >= BIMG * NPROP) return;
    const int img = pid / NPROP;
    const float fw = (float)imw[0], fh = (float)imh[0];
    const float* lrow = logits + (size_t)pid * NCLS;
    float v0 = lrow[lane];
    float v1 = (lane < 27) ? lrow[lane + 64] : -3.0e38f;
    float mx = fmaxf(v0, v1);
#pragma unroll
    for (int o = 32; o > 0; o >>= 1) mx = fmaxf(mx, __shfl_xor(mx, o));
    float es = expf(v0 - mx) + ((lane < 27) ? expf(v1 - mx) : 0.0f);
#pragma unroll
    for (int o = 32; o > 0; o >>= 1) es += __shfl_xor(es, o);
    const float thr = mx + logf(es) - 2.9967323f;   // ln(0.05) - 1e-3 margin
    float4 p = reinterpret_cast<const float4*>(props)[pid];
    const float w = p.z - p.x, h = p.w - p.y;
    const float cx = p.x + 0.5f * w, cy = p.y + 0.5f * h;
    const float4* rrow = reinterpret_cast<const float4*>(reg) + (size_t)pid * NCLS;
    const int n = pid - img * NPROP;
    u32* co = cand_ord + (size_t)img * MCAND + (size_t)n * CM1;
#pragma unroll
    for (int batch = 0; batch < 2; ++batch) {
        int ci = lane + batch * 64;
        if (ci < CM1) {
            int c = ci + 1;
            float l = lrow[c];
            u32 o = 0u;
            if (l > thr) {                        // rare (~2% of lanes)
                float sc = expf(l - mx) / es;     // exact, same as before
                float4 rg = rrow[c];
                float bx[4];
                decode_clip(rg, w, h, cx, cy, fw, fh, bx);
                bool valid = (sc > SCORE_T) && (bx[2] - bx[0] >= 1.0f) && (bx[3] - bx[1] >= 1.0f);
                if (valid) {
                    o = __float_as_uint(sc) | 0x80000000u;  // sc > 0 always
                    u32 t = (u32)img * MCAND + (u32)n * CM1 + (u32)ci;
                    int rep = (int)((t >> 8) & (NREP - 1));
                    atomicAdd(&histrep[((size_t)rep * BIMG + img) * NBUCKET + (o >> 20)], 1u);
                }
            }
            co[ci] = o;
        }
    }
}

// K2: one 256-thread block per image. Sums the NREP histogram replicas,
// block-scans in descending-bucket order -> start[], per-rep sub-offsets
// startrep[], histtot[], threshold bucket T, V, fillneed, AND a worklist of
// buckets needing a sort (cnt>=2 && start<KPRE) for k4 load balancing.
__global__ __launch_bounds__(256) void k2_scan(
    const u32* __restrict__ histrep, u32* __restrict__ histtot,
    u32* __restrict__ start, u32* __restrict__ startrep, u32* __restrict__ meta,
    u32* __restrict__ wlist) {
    const int img = blockIdx.x;
    const int td = threadIdx.x;
    const int lane = td & 63, wv = td >> 6;
    u32 cnt[16]; u32 tsum = 0;
#pragma unroll
    for (int k = 0; k < 16; ++k) {
        const int bk = NBUCKET - 1 - (td * 16 + k);
        u32 c = 0;
#pragma unroll
        for (int r = 0; r < NREP; ++r)
            c += histrep[((size_t)r * BIMG + img) * NBUCKET + bk];
        cnt[k] = c; tsum += c;
    }
    u32 inc = tsum;
#pragma unroll
    for (int o = 1; o < 64; o <<= 1) { u32 t = __shfl_up(inc, o); if (lane >= o) inc += t; }
    __shared__ u32 wsum[4];
    __shared__ u32 TbkS, Vs;
    if (td == 0) TbkS = 0u;
    if (lane == 63) wsum[wv] = inc;
    __syncthreads();
    u32 wbase = 0;
    for (int i = 0; i < wv; ++i) wbase += wsum[i];
    if (td == 255) Vs = wbase + inc;
    const u32 excl0 = wbase + inc - tsum;
    u32 excl = excl0;
#pragma unroll
    for (int k = 0; k < 16; ++k) {
        const int bk = NBUCKET - 1 - (td * 16 + k);
        const u32 c = cnt[k];
        start[img * NBUCKET + bk] = excl;
        histtot[img * NBUCKET + bk] = c;
        u32 sub = excl;
#pragma unroll
        for (int r = 0; r < NREP; ++r) {
            startrep[((size_t)r * BIMG + img) * NBUCKET + bk] = sub;
            sub += histrep[((size_t)r * BIMG + img) * NBUCKET + bk];
        }
        if (c > 0 && excl < KPRE && excl + c >= KPRE) TbkS = (u32)bk;  // <=1 writer
        excl += c;
    }
    // ---- worklist emission: buckets with cnt>=2 && start<KPRE ----
    u32 qcnt = 0;
    {
        u32 e = excl0;
#pragma unroll
        for (int k = 0; k < 16; ++k) {
            if (cnt[k] >= 2 && e < KPRE) ++qcnt;
            e += cnt[k];
        }
    }
    u32 qinc = qcnt;
#pragma unroll
    for (int o = 1; o < 64; o <<= 1) { u32 t = __shfl_up(qinc, o); if (lane >= o) qinc += t; }
    __shared__ u32 qws[4];
    if (lane == 63) qws[wv] = qinc;
    __syncthreads();
    u32 qbase = 0;
    for (int i = 0; i < wv; ++i) qbase += qws[i];
    u32 qoff = qbase + qinc - qcnt;
    {
        u32 e = excl0;
#pragma unroll
        for (int k = 0; k < 16; ++k) {
            const int bk = NBUCKET - 1 - (td * 16 + k);
            if (cnt[k] >= 2 && e < KPRE && qoff < WLCAP) wlist[img * WLCAP + (qoff++)] = (u32)bk;
            e += cnt[k];
        }
    }
    if (td == 255) meta[img * 8 + 3] = qbase + qinc;   // worklist count
    __syncthreads();
    if (td == 0) {
        u32 V = Vs;
        meta[img * 8 + 0] = V;
        meta[img * 8 + 1] = TbkS;
        meta[img * 8 + 2] = (V < KPRE) ? (KPRE - V) : 0u;
    }
}

// K3: compact candidates in buckets >= T into sel[], position = per-rep
// sub-range start + per-rep atomic counter (rep = blockIdx & 7).
__global__ __launch_bounds__(256) void k3_compact(
    const u32* __restrict__ cand_ord, const u32* __restrict__ startrep,
    const u32* __restrict__ meta, u32* __restrict__ bcntrep, u64* __restrict__ sel) {
    const u32 t = blockIdx.x * 256 + threadIdx.x;
    const int rep = (int)(blockIdx.x & (NREP - 1));   // == (t>>8)&7
    if (t >= (u32)(BIMG * MCAND)) return;
    const int img = t / MCAND;
    const u32 idx = t - (u32)img * MCAND;
    const u32 o = cand_ord[t];
    if (!o) return;
    const u32 bk = o >> 20;
    if (bk < meta[img * 8 + 1]) return;
    const size_t ri = ((size_t)rep * BIMG + img) * NBUCKET + bk;
    const u32 pos = startrep[ri] + atomicAdd(&bcntrep[ri], 1u);
    if (pos < SELCAP)
        sel[(size_t)img * SELCAP + pos] = ((u64)o << 32) | (u32)(~idx);
}

// K3b: rare path — fewer than KPRE valid: fill remaining slots with invalid
// candidates (score -1) in ascending-index order (lax.top_k tie semantics).
__global__ __launch_bounds__(64) void k3b_fill(
    const u32* __restrict__ cand_ord, const u32* __restrict__ meta, u64* __restrict__ sel) {
    const int img = blockIdx.x;
    const u32 need = meta[img * 8 + 2];
    if (need == 0) return;
    const u32 V = meta[img * 8 + 0];
    const int lane = threadIdx.x;
    const u32 ORDN1 = 0x407FFFFFu;  // ord_of(-1.0f)
    u32 filled = 0;
    for (u32 b0 = 0; b0 < MCAND && filled < need; b0 += 64) {
        u32 idx = b0 + lane;
        bool inv = (idx < MCAND) && (cand_ord[(size_t)img * MCAND + idx] == 0u);
        u64 bal = __ballot(inv);
        u32 pre = (u32)__popcll(bal & ((1ull << lane) - 1ull));
        if (inv && (filled + pre) < need)
            sel[(size_t)img * SELCAP + V + filled + pre] = ((u64)ORDN1 << 32) | (u32)(~idx);
        filled += (u32)__popcll(bal);
    }
}

// K4: worklist-driven. Grid (64, BIMG); block x sorts worklist entries
// x, x+64, ... (one LDS bitonic per bucket segment).
__global__ __launch_bounds__(256) void k4_sortseg(
    const u32* __restrict__ histtot, const u32* __restrict__ start,
    const u32* __restrict__ meta, const u32* __restrict__ wlist, u64* __restrict__ sel) {
    __shared__ u64 arr[4096];
    const int img = blockIdx.y;
    const int tid = threadIdx.x;
    const u32 wcount = meta[img * 8 + 3];
    for (u32 wi = blockIdx.x; wi < wcount; wi += gridDim.x) {
        const u32 bk = (wi < WLCAP) ? wlist[img * WLCAP + wi] : 0u;
        u32 cnt = histtot[img * NBUCKET + bk];       // uniform across block
        u32 st = start[img * NBUCKET + bk];
        if (cnt < 2 || st >= KPRE) continue;         // defensive; wlist guarantees
        if (st + cnt > SELCAP) cnt = SELCAP - st;
        if (cnt > 4096) cnt = 4096;                  // pathological only
        int n = 1;
        while (n < (int)cnt) n <<= 1;
        u64* seg = sel + (size_t)img * SELCAP + st;
        for (int i = tid; i < n; i += 256) arr[i] = (i < (int)cnt) ? seg[i] : 0ull;
        __syncthreads();
        for (int k = 2; k <= n; k <<= 1)
            for (int j = k >> 1; j > 0; j >>= 1) {
                for (int i = tid; i < n; i += 256) {
                    int ixj = i ^ j;
                    if (ixj > i) {
                        u64 a = arr[i], b = arr[ixj];
                        bool swp = ((i & k) == 0) ? (a < b) : (a > b);
                        if (swp) { arr[i] = b; arr[ixj] = a; }
                    }
                }
                __syncthreads();
            }
        for (int i = tid; i < (int)cnt; i += 256) seg[i] = arr[i];
        __syncthreads();
    }
}

// K5: gather the top-2048: re-decode boxes, store score/label/valid, compute
// max coordinate and class-offset shifted boxes exactly as the reference.
__global__ __launch_bounds__(256) void k5_gather(
    const u64* __restrict__ sel, const float* __restrict__ reg, const float* __restrict__ props,
    const int* __restrict__ imh, const int* __restrict__ imw,
    float* __restrict__ tbox, float* __restrict__ tsb, float* __restrict__ tsc,
    int* __restrict__ tlb, u32* __restrict__ tvl) {
    const int img = blockIdx.x;
    const int tid = threadIdx.x;
    const float fw = (float)imw[0], fh = (float)imh[0];
    float bx[8][4];
    int lab[8];
    float lm = -3.0e38f;
#pragma unroll
    for (int t = 0; t < 8; ++t) {
        int s = t * 256 + tid;
        u64 key = sel[(size_t)img * SELCAP + s];
        u32 o = (u32)(key >> 32);
        u32 idx = ~((u32)key);
        u32 b = (o & 0x80000000u) ? (o & 0x7FFFFFFFu) : ~o;
        float sc = __uint_as_float(b);               // exact masked score roundtrip
        u32 n = idx / CM1;
        int c = (int)(idx - n * CM1) + 1;
        int pid = img * NPROP + (int)n;
        float4 p = reinterpret_cast<const float4*>(props)[pid];
        float w = p.z - p.x, h = p.w - p.y;
        float cx = p.x + 0.5f * w, cy = p.y + 0.5f * h;
        float4 rg = reinterpret_cast<const float4*>(reg)[(size_t)pid * NCLS + c];
        decode_clip(rg, w, h, cx, cy, fw, fh, bx[t]);
        lab[t] = c;
        lm = fmaxf(lm, fmaxf(fmaxf(bx[t][0], bx[t][1]), fmaxf(bx[t][2], bx[t][3])));
        reinterpret_cast<float4*>(tbox)[(size_t)img * KPRE + s] =
            make_float4(bx[t][0], bx[t][1], bx[t][2], bx[t][3]);
        tsc[(size_t)img * KPRE + s] = sc;
        tlb[(size_t)img * KPRE + s] = c;
        tvl[(size_t)img * KPRE + s] = (sc > SCORE_T) ? 1u : 0u;
    }
#pragma unroll
    for (int o2 = 32; o2 > 0; o2 >>= 1) lm = fmaxf(lm, __shfl_xor(lm, o2));
    __shared__ float wm[4];
    if ((tid & 63) == 0) wm[tid >> 6] = lm;
    __syncthreads();
    float mplus = fmaxf(fmaxf(wm[0], wm[1]), fmaxf(wm[2], wm[3])) + 1.0f;
#pragma unroll
    for (int t = 0; t < 8; ++t) {
        int s = t * 256 + tid;
        float off = (float)lab[t] * mplus;
        reinterpret_cast<float4*>(tsb)[(size_t)img * KPRE + s] =
            make_float4(bx[t][0] + off, bx[t][1] + off, bx[t][2] + off, bx[t][3] + off);
    }
}

// K6: suppression bitmask. Block = 64 rows x 64 cols; bit set iff
// iou(shifted_i, shifted_j) > thresh and j > i (reference formula verbatim).
// Strictly-below-diagonal tiles (bx < by) have no j>i pairs: skipped; the
// pre-k6 memset of the mask region supplies their zeros.
__global__ __launch_bounds__(64) void k6_mask(
    const float* __restrict__ tsb, u64* __restrict__ mask) {
    if (blockIdx.x < blockIdx.y) return;
    const int img = blockIdx.z;
    const int j0 = blockIdx.x * 64;
    const int i0 = blockIdx.y * 64;
    const int tid = threadIdx.x;
    __shared__ float4 cb[64];
    __shared__ float ca[64];
    float4 c = reinterpret_cast<const float4*>(tsb)[(size_t)img * KPRE + j0 + tid];
    cb[tid] = c;
    ca[tid] = (c.z - c.x) * (c.w - c.y);
    __syncthreads();
    const int i = i0 + tid;
    float4 r = reinterpret_cast<const float4*>(tsb)[(size_t)img * KPRE + i];
    float ra = (r.z - r.x) * (r.w - r.y);
    u64 bits = 0ull;
#pragma unroll 8
    for (int jj = 0; jj < 64; ++jj) {
        int j = j0 + jj;
        float4 cc = cb[jj];
        float wv = fmaxf(fminf(r.z, cc.z) - fmaxf(r.x, cc.x), 0.0f);
        float hv = fmaxf(fminf(r.w, cc.w) - fmaxf(r.y, cc.y), 0.0f);
        float inter = wv * hv;
        float iou = inter / ((ra + ca[jj]) - inter);   // NaN compares false, like jnp
        if ((iou > NMS_T) && (j > i)) bits |= (1ull << jj);
    }
    mask[((size_t)img * KPRE + i) * 32 + (j0 >> 6)] = bits;
}

// ---- K7: SALU serial chain + double-buffered LDS DMA + b128 apply +
//      EARLY EXIT: only the first DETS kept rows matter downstream (k8 takes
//      the first-100 kept in order). Kept bits of processed blocks are final,
//      so once cumulative kept >= DETS we zero remaining keep words and stop
//      (typically after 2-3 of 32 stages).
__device__ __forceinline__ u64 rdlane64(u64 v, int l) {
    u32 lo = (u32)__builtin_amdgcn_readlane((int)(u32)v, l);
    u32 hi = (u32)__builtin_amdgcn_readlane((int)(u32)(v >> 32), l);
    return ((u64)hi << 32) | lo;
}

__device__ __forceinline__ void g2l16(const void* g, void* l) {
    __builtin_amdgcn_global_load_lds(
        (const __attribute__((address_space(1))) void*)g,
        (__attribute__((address_space(3))) void*)l, 16, 0, 0);
}

__global__ __launch_bounds__(64) void k7_nms(
    const u64* __restrict__ mask, const u32* __restrict__ tvl, u64* __restrict__ keepw) {
    __shared__ u64 lbuf[2][2048];        // 2 x 16 KB double buffer
    const int img = blockIdx.x;
    const int lane = threadIdx.x;
    const int lg = lane >> 4;            // row-offset selector 0..3
    const u64* mrow = mask + (size_t)img * KPRE * 32;

    // init: ballot per word (uniform); acc pair covers words 2(l&15), +1.
    u64 accx = 0ull, accy = 0ull, rp = 0ull;
    for (int w = 0; w < 32; ++w) {
        bool tv = tvl[(size_t)img * KPRE + w * 64 + lane] != 0u;
        u64 iw = ~__ballot(tv);          // uniform across wave
        if (w == 0) rp = iw;
        if ((lane & 15) == (w >> 1)) { if (w & 1) accy = iw; else accx = iw; }
    }

    // pre-loop: DMA stage 0 into buf0; diag for stage 0
    {
        const char* gsrc = (const char*)mrow + (size_t)lane * 16;
#pragma unroll
        for (int t = 0; t < 16; ++t)
            g2l16(gsrc + (size_t)t * 1024, (char*)&lbuf[0][0] + (size_t)t * 1024);
    }
    u64 diag = mrow[(size_t)lane * 32];  // word 0 of row 'lane'

    u32 tk = 0;                          // cumulative kept
    int bcut = 31;                       // last processed block

#pragma unroll 1
    for (int b = 0; b < 32; ++b) {
        const size_t base32 = (size_t)b * 2048;
        const u64* cbuf = &lbuf[b & 1][0];

        // ---- issue next stage's diag prefetch FIRST, then its DMA ----
        u64 diagn = 0ull;
        if (b + 1 < 32) {
            diagn = mrow[base32 + 2048 + (size_t)lane * 32 + (b + 1)];
            const char* gsrc = (const char*)(mrow + base32 + 2048) + (size_t)lane * 16;
            char* nb_l = (char*)&lbuf[(b + 1) & 1][0];
#pragma unroll
            for (int t = 0; t < 16; ++t)
                g2l16(gsrc + (size_t)t * 1024, nb_l + (size_t)t * 1024);
        }

        // ---- serial in-block recurrence (scalar chain) ----
        u64 A = rp;
#pragma unroll
        for (int u = 0; u < 64; ++u) {
            u64 row = rdlane64(diag, u);
            if (!((A >> u) & 1ull)) A |= row;      // row has only bits > u in-block
        }
        const u64 keptw = ~A;

        // ---- wait for CURRENT buffer's DMA (counted), apply from LDS ----
        if (b + 1 < 32) asm volatile("s_waitcnt vmcnt(17)" ::: "memory");
        else            asm volatile("s_waitcnt vmcnt(0)" ::: "memory");

#define LDV(K) u64x2 v##K = *(const u64x2*)&cbuf[128 * (K) + 2 * lane];
#define PRV(K) { u32 nib = (u32)(keptw >> (4 * (K))) & 15u; \
                 u32 kb = (nib >> lg) & 1u; \
                 accx |= kb ? v##K.x : 0ull; accy |= kb ? v##K.y : 0ull; }
        LDV(0) LDV(1) LDV(2) LDV(3)
        LDV(4) LDV(5) LDV(6) LDV(7)     PRV(0) PRV(1) PRV(2) PRV(3)
        LDV(8) LDV(9) LDV(10) LDV(11)   PRV(4) PRV(5) PRV(6) PRV(7)
        LDV(12) LDV(13) LDV(14) LDV(15) PRV(8) PRV(9) PRV(10) PRV(11)
        PRV(12) PRV(13) PRV(14) PRV(15)
#undef LDV
#undef PRV

        tk += (u32)__popcll(keptw);
        if (tk >= (u32)DETS) { bcut = b; break; }   // first DETS kept are final

        // ---- seed word b+1 from the 4 partials holding that word ----
        const int nb2 = b + 1;
        if (nb2 < 32) {
            u64 asel = (nb2 & 1) ? accy : accx;
            const int sl = (nb2 >> 1) & 15;
            rp = rdlane64(asel, sl) | rdlane64(asel, sl + 16) |
                 rdlane64(asel, sl + 32) | rdlane64(asel, sl + 48);
        }
        diag = diagn;
    }

    // drain any in-flight DMA before LDS teardown / endpgm
    asm volatile("s_waitcnt vmcnt(0)" ::: "memory");

    // merge 4-way partials; words > bcut unprocessed -> not kept (0)
    accx |= __shfl_xor(accx, 16); accx |= __shfl_xor(accx, 32);
    accy |= __shfl_xor(accy, 16); accy |= __shfl_xor(accy, 32);
    if (lane < 16) {
        keepw[img * 32 + 2 * lane]     = (2 * lane     <= bcut) ? ~accx : 0ull;
        keepw[img * 32 + 2 * lane + 1] = (2 * lane + 1 <= bcut) ? ~accy : 0ull;
    }
}

// K8 v2: NO SORT. tsc[s] is descending in s (k4's sort) and XLA top_k
// tie-breaks ascending index, so top_k(where(keep,score,-1), 100) == the
// first 100 kept s in ascending order. One wave per image: popcount prefix
// over the 32 keep words + compaction writes; slots beyond kept-count get
// (0,0,-1) exactly like the reference's fvalid=false path.
__global__ __launch_bounds__(64) void k8_select(
    const u64* __restrict__ keepw, const float* __restrict__ tsc,
    const float* __restrict__ tbox, const int* __restrict__ tlb,
    float* __restrict__ out) {
    const int img = blockIdx.x;
    const int lane = threadIdx.x;
    u64 kw = (lane < 32) ? keepw[img * 32 + lane] : 0ull;
    u32 cnt = (u32)__popcll(kw);
    u32 inc = cnt;
#pragma unroll
    for (int o = 1; o < 64; o <<= 1) { u32 t = __shfl_up(inc, o); if (lane >= o) inc += t; }
    const u32 excl = inc - cnt;
    const u32 total = (u32)__shfl(inc, 63);

    float* ob0 = out + (size_t)img * DETS * 4;
    float* os0 = out + (size_t)BIMG * DETS * 4 + (size_t)img * DETS;
    float* ol0 = out + (size_t)BIMG * DETS * 5 + (size_t)img * DETS;

    // zero-fill slots r in [total, DETS) — disjoint from kept writes
#pragma unroll
    for (int t = 0; t < 2; ++t) {
        u32 r = (u32)lane + (u32)t * 64;
        if (r < DETS && r >= total) {
            reinterpret_cast<float4*>(ob0)[r] = make_float4(0.f, 0.f, 0.f, 0.f);
            os0[r] = 0.0f;
            ol0[r] = -1.0f;
        }
    }

    // kept writes: lane l holds word l; its bits' ranks start at excl
    u64 w = kw;
    u32 r = excl;
    while (w != 0ull && r < DETS) {
        int p = __ffsll((unsigned long long)w) - 1;
        w &= (w - 1ull);
        u32 s = (u32)lane * 64u + (u32)p;
        reinterpret_cast<float4*>(ob0)[r] =
            reinterpret_cast<const float4*>(tbox)[(size_t)img * KPRE + s];
        os0[r] = tsc[(size_t)img * KPRE + s];
        ol0[r] = (float)tlb[(size_t)img * KPRE + s];
        ++r;
    }
}

extern "C" void kernel_launch(void* const* d_in, const int* in_sizes, int n_in,
                              void* d_out, int out_size, void* d_ws, size_t ws_size,
                              hipStream_t stream) {
    const float* logits = (const float*)d_in[0];
    const float* reg    = (const float*)d_in[1];
    const float* props  = (const float*)d_in[2];
    const int*   imh    = (const int*)d_in[3];
    const int*   imw    = (const int*)d_in[4];
    float* out = (float*)d_out;
    char* ws = (char*)d_ws;
    if (ws_size < WS_NEED) return;  // ~16.8 MB needed

    u32* histrep  = (u32*)(ws + HISTREP_OFF);
    u32* bcntrep  = (u32*)(ws + BCNTREP_OFF);
    u32* meta     = (u32*)(ws + META_OFF);
    u32* start    = (u32*)(ws + START_OFF);
    u32* histtot  = (u32*)(ws + HISTTOT_OFF);
    u32* startrep = (u32*)(ws + STARTREP_OFF);
    u64* sel  = (u64*)(ws + SEL_OFF);
    float* tbox = (float*)(ws + TBOX_OFF);
    float* tsb  = (float*)(ws + TSB_OFF);
    float* tsc  = (float*)(ws + TSC_OFF);
    int*   tlb  = (int*)(ws + TLB_OFF);
    u32*   tvl  = (u32*)(ws + TVL_OFF);
    u64*   keepw = (u64*)(ws + KEEP_OFF);
    u32*   wlist = (u32*)(ws + WLIST_OFF);
    u32*   cand_ord = (u32*)(ws + UNION_OFF);   // overlaid with mask
    u64*   mask = (u64*)(ws + UNION_OFF);       // memset + k6 after k3b's last read

    hipMemsetAsync(d_ws, 0, ZERO_BYTES, stream);  // histrep, bcntrep, meta

    k1_score_hist<<<BIMG * NPROP / 4, 256, 0, stream>>>(logits, reg, props, imh, imw,
                                                        histrep, cand_ord);
    k2_scan<<<BIMG, 256, 0, stream>>>(histrep, histtot, start, startrep, meta, wlist);
    k3_compact<<<(BIMG * MCAND) / 256, 256, 0, stream>>>(cand_ord, startrep, meta, bcntrep, sel);
    k3b_fill<<<BIMG, 64, 0, stream>>>(cand_ord, meta, sel);
    // cand_ord dead; zero the mask overlay (sub-diagonal tiles skip writes in k6)
    hipMemsetAsync(mask, 0, MASK_BYTES, stream);
    k4_sortseg<<<dim3(64, BIMG), 256, 0, stream>>>(histtot, start, meta, wlist, sel);
    k5_gather<<<BIMG, 256, 0, stream>>>(sel, reg, props, imh, imw, tbox, tsb, tsc, tlb, tvl);
    k6_mask<<<dim3(32, 32, BIMG), 64, 0, stream>>>(tsb, mask);
    k7_nms<<<BIMG, 64, 0, stream>>>(mask, tvl, keepw);
    k8_select<<<BIMG, 64, 0, stream>>>(keepw, tsc, tbox, tlb, out);
}